// Round 12
// baseline (24575.386 us; speedup 1.0000x reference)
//
#include <hip/hip_runtime.h>
#include <cstdint>
#include <cstddef>

#define N_OBJ 2048
#define N_TOT 2064
#define NUM_CLASSES 151
#define EMBED 200
#define HID 512
#define OBJ_DIM 4096
#define POS 128
#define OBJ_IN 4424   // 4096+200+128
#define DEC_IN 4936   // 512+4424
#define EDGE_IN 4808  // 200+4096+512
#define G4 2048       // 4*HID
#define NBLK 32       // scan blocks; 4 waves each; block owns 16 h-dims
#define DATA_SPIN 20000

// ----------------------------------------------------------------------------
// utility kernels
// ----------------------------------------------------------------------------
__global__ void init_sync_kernel(unsigned* p, int n) {
  int i = blockIdx.x * blockDim.x + threadIdx.x;
  int stride = gridDim.x * blockDim.x;
  for (; i < n; i += stride) p[i] = 0u;
}

__global__ void copy4_kernel(const float4* __restrict__ src, float4* __restrict__ dst, long n4) {
  long i = blockIdx.x * (long)blockDim.x + threadIdx.x;
  long stride = (long)gridDim.x * blockDim.x;
  for (; i < n4; i += stride) dst[i] = src[i];
}

// feats[r][0:4096] = x[r]
__global__ void copy_x_kernel(const float* __restrict__ x, float* __restrict__ feats) {
  long i = blockIdx.x * (long)blockDim.x + threadIdx.x; // over 2048*1024 float4
  if (i >= (long)N_OBJ * (OBJ_DIM / 4)) return;
  long r = i >> 10, c = i & 1023;
  reinterpret_cast<float4*>(feats + r * (long)OBJ_IN)[c] =
      reinterpret_cast<const float4*>(x + r * (long)OBJ_DIM)[c];
}

// feats[r][4096:4296] = obj_dists_in[r] @ embed1
__global__ void obj_embed_kernel(const float* __restrict__ dists,
                                 const float* __restrict__ embed1,
                                 float* __restrict__ feats) {
  int r = blockIdx.x;
  __shared__ float drow[NUM_CLASSES];
  for (int c = threadIdx.x; c < NUM_CLASSES; c += blockDim.x)
    drow[c] = dists[(size_t)r * NUM_CLASSES + c];
  __syncthreads();
  for (int j = threadIdx.x; j < EMBED; j += blockDim.x) {
    float s = 0.f;
    for (int k = 0; k < NUM_CLASSES; ++k)
      s = fmaf(drow[k], embed1[(size_t)k * EMBED + j], s);
    feats[(size_t)r * OBJ_IN + OBJ_DIM + j] = s;
  }
}

// feats[r][4296:4424] = relu(BN(box@W1+b1)@W2+b2)
__global__ void pos_kernel(const float* __restrict__ box,
                           const float* __restrict__ W1, const float* __restrict__ b1,
                           const float* __restrict__ gamma, const float* __restrict__ beta,
                           const float* __restrict__ mean, const float* __restrict__ var,
                           const float* __restrict__ W2, const float* __restrict__ b2,
                           float* __restrict__ feats) {
  int r = blockIdx.x;
  __shared__ float h[32];
  __shared__ float bx[9];
  if (threadIdx.x < 9) bx[threadIdx.x] = box[(size_t)r * 9 + threadIdx.x];
  __syncthreads();
  if (threadIdx.x < 32) {
    float s = b1[threadIdx.x];
    for (int k = 0; k < 9; ++k) s = fmaf(bx[k], W1[k * 32 + threadIdx.x], s);
    s = (s - mean[threadIdx.x]) * (1.f / sqrtf(var[threadIdx.x] + 1e-5f)) * gamma[threadIdx.x]
        + beta[threadIdx.x];
    h[threadIdx.x] = s;
  }
  __syncthreads();
  int j = threadIdx.x;
  if (j < POS) {
    float s = b2[j];
    for (int k = 0; k < 32; ++k) s = fmaf(h[k], W2[k * POS + j], s);
    feats[(size_t)r * OBJ_IN + OBJ_DIM + EMBED + j] = fmaxf(s, 0.f);
  }
}

// ----------------------------------------------------------------------------
// GEMM descriptor + tile body (used by standalone and fused kernels)
// C[M,N](ldc) = A[M,K](lda) @ B[K,N](ldb)  (+bias if !acc, += if acc)
// ----------------------------------------------------------------------------
struct GemmDesc {
  const float* A; const float* B; const float* bias; float* C;
  int lda, ldb, ldc, M, N, K, acc, nbx, ntot;
};

__device__ void gemm_tile(float (*As)[68], float (*Bs)[64], const GemmDesc d, int bx) {
  const int by = bx / d.nbx, bxx = bx - by * d.nbx;
  const int row0 = by * 64, col0 = bxx * 64;
  const int tid = threadIdx.x;
  const int tx = tid & 15, ty = tid >> 4;
  float acc[4][4] = {};

  for (int k0 = 0; k0 < d.K; k0 += 16) {
#pragma unroll
    for (int l = 0; l < 4; ++l) {
      int idx = tid + l * 256;
      int m = idx >> 4, kk = idx & 15;
      int gm = row0 + m, gk = k0 + kk;
      As[kk][m] = (gm < d.M && gk < d.K) ? d.A[(size_t)gm * d.lda + gk] : 0.f;
    }
#pragma unroll
    for (int l = 0; l < 4; ++l) {
      int idx = tid + l * 256;
      int kk = idx >> 6, n = idx & 63;
      int gk = k0 + kk, gn = col0 + n;
      Bs[kk][n] = (gk < d.K && gn < d.N) ? d.B[(size_t)gk * d.ldb + gn] : 0.f;
    }
    __syncthreads();
#pragma unroll
    for (int kk = 0; kk < 16; ++kk) {
      float4 a = *reinterpret_cast<const float4*>(&As[kk][ty * 4]);
      float4 b = *reinterpret_cast<const float4*>(&Bs[kk][tx * 4]);
      acc[0][0] = fmaf(a.x, b.x, acc[0][0]); acc[0][1] = fmaf(a.x, b.y, acc[0][1]);
      acc[0][2] = fmaf(a.x, b.z, acc[0][2]); acc[0][3] = fmaf(a.x, b.w, acc[0][3]);
      acc[1][0] = fmaf(a.y, b.x, acc[1][0]); acc[1][1] = fmaf(a.y, b.y, acc[1][1]);
      acc[1][2] = fmaf(a.y, b.z, acc[1][2]); acc[1][3] = fmaf(a.y, b.w, acc[1][3]);
      acc[2][0] = fmaf(a.z, b.x, acc[2][0]); acc[2][1] = fmaf(a.z, b.y, acc[2][1]);
      acc[2][2] = fmaf(a.z, b.z, acc[2][2]); acc[2][3] = fmaf(a.z, b.w, acc[2][3]);
      acc[3][0] = fmaf(a.w, b.x, acc[3][0]); acc[3][1] = fmaf(a.w, b.y, acc[3][1]);
      acc[3][2] = fmaf(a.w, b.z, acc[3][2]); acc[3][3] = fmaf(a.w, b.w, acc[3][3]);
    }
    __syncthreads();
  }
#pragma unroll
  for (int i = 0; i < 4; ++i) {
    int gm = row0 + ty * 4 + i;
    if (gm >= d.M) continue;
#pragma unroll
    for (int j = 0; j < 4; ++j) {
      int gn = col0 + tx * 4 + j;
      if (gn >= d.N) continue;
      size_t o = (size_t)gm * d.ldc + gn;
      if (d.acc) d.C[o] += acc[i][j];
      else d.C[o] = acc[i][j] + (d.bias ? d.bias[gn] : 0.f);
    }
  }
}

template <int ACC>
__global__ __launch_bounds__(256)
void gemm_kernel(const float* A, int lda, const float* B, int ldb, const float* bias,
                 float* C, int ldc, int M, int N, int K) {
  __shared__ __align__(16) float As[16][68];
  __shared__ __align__(16) float Bs[16][64];
  GemmDesc d{A, B, bias, C, lda, ldb, ldc, M, N, K, ACC, (int)gridDim.x, 0};
  gemm_tile(As, Bs, d, blockIdx.x + blockIdx.y * gridDim.x);
}

// epre[r] += embed2[pred[r]] @ B   (M=2048, K=EMBED, ACC)
__global__ __launch_bounds__(256)
void gemm_gather_kernel(const float* __restrict__ embed2, const int* __restrict__ pred,
                        const float* __restrict__ B, float* __restrict__ C,
                        int M, int N, int K) {
  __shared__ __align__(16) float As[16][68];
  __shared__ __align__(16) float Bs[16][64];
  const int row0 = blockIdx.y * 64, col0 = blockIdx.x * 64;
  const int tid = threadIdx.x;
  const int tx = tid & 15, ty = tid >> 4;
  float acc[4][4] = {};
  for (int k0 = 0; k0 < K; k0 += 16) {
#pragma unroll
    for (int l = 0; l < 4; ++l) {
      int idx = tid + l * 256;
      int m = idx >> 4, kk = idx & 15;
      int gm = row0 + m, gk = k0 + kk;
      As[kk][m] = (gm < M && gk < K) ? embed2[(size_t)pred[gm] * EMBED + gk] : 0.f;
    }
#pragma unroll
    for (int l = 0; l < 4; ++l) {
      int idx = tid + l * 256;
      int kk = idx >> 6, n = idx & 63;
      int gk = k0 + kk, gn = col0 + n;
      Bs[kk][n] = (gk < K && gn < N) ? B[(size_t)gk * G4 + gn] : 0.f;
    }
    __syncthreads();
#pragma unroll
    for (int kk = 0; kk < 16; ++kk) {
      float4 a = *reinterpret_cast<const float4*>(&As[kk][ty * 4]);
      float4 b = *reinterpret_cast<const float4*>(&Bs[kk][tx * 4]);
      acc[0][0] = fmaf(a.x, b.x, acc[0][0]); acc[0][1] = fmaf(a.x, b.y, acc[0][1]);
      acc[0][2] = fmaf(a.x, b.z, acc[0][2]); acc[0][3] = fmaf(a.x, b.w, acc[0][3]);
      acc[1][0] = fmaf(a.y, b.x, acc[1][0]); acc[1][1] = fmaf(a.y, b.y, acc[1][1]);
      acc[1][2] = fmaf(a.y, b.z, acc[1][2]); acc[1][3] = fmaf(a.y, b.w, acc[1][3]);
      acc[2][0] = fmaf(a.z, b.x, acc[2][0]); acc[2][1] = fmaf(a.z, b.y, acc[2][1]);
      acc[2][2] = fmaf(a.z, b.z, acc[2][2]); acc[2][3] = fmaf(a.z, b.w, acc[2][3]);
      acc[3][0] = fmaf(a.w, b.x, acc[3][0]); acc[3][1] = fmaf(a.w, b.y, acc[3][1]);
      acc[3][2] = fmaf(a.w, b.z, acc[3][2]); acc[3][3] = fmaf(a.w, b.w, acc[3][3]);
    }
    __syncthreads();
  }
#pragma unroll
  for (int i = 0; i < 4; ++i) {
    int gm = row0 + ty * 4 + i;
    if (gm >= M) continue;
#pragma unroll
    for (int j = 0; j < 4; ++j) {
      int gn = col0 + tx * 4 + j;
      if (gn >= N) continue;
      C[(size_t)gm * G4 + gn] += acc[i][j];
    }
  }
}

// ----------------------------------------------------------------------------
// persistent LSTM scan body (R11-proven, byte-identical logic).
// 32 blocks x 4 waves; tagged-pair exchange {tag=s+1, h} via relaxed/agent
// atomics; wave0 single-poller with s_sleep(2) backoff; bounded + sticky
// dead-latch (worst case loud absmax fail, never a hang).
// ----------------------------------------------------------------------------
struct ScanSmem {
  float4 w4[4][32][64];   // 128 KB: per-wave [k4][lane]
  float hl[532];          // block-shared h, 4x(128+4 pad)
};

__device__ void scan_body(ScanSmem& sm, const float* __restrict__ pre,
                          const float* __restrict__ Wh, float* __restrict__ hs,
                          unsigned long long* hg, int T) {
  const int tid = threadIdx.x;
  const int wv = tid >> 6;
  const int l = tid & 63;

  const int q = l >> 2;
  const int qt = l & 3;
  const int dq = q >> 2;
  const int gq = q & 3;
  const int d0w = blockIdx.x * 16 + wv * 4;
  const int colw = gq * HID + d0w + dq;

  {
    const float* base = Wh + (size_t)(qt * 128) * G4 + colw;
#pragma unroll 4
    for (int j4 = 0; j4 < 32; ++j4) {
      float4 t;
      t.x = base[(size_t)(4 * j4 + 0) * G4];
      t.y = base[(size_t)(4 * j4 + 1) * G4];
      t.z = base[(size_t)(4 * j4 + 2) * G4];
      t.w = base[(size_t)(4 * j4 + 3) * G4];
      sm.w4[wv][j4][l] = t;
    }
  }
  for (int i = tid; i < 532; i += 256) sm.hl[i] = 0.f;
  __syncthreads();

  float creg = 0.f;
  bool dead = false;

  for (int s = 0; s < T; ++s) {
    float pre_v = pre[(size_t)s * G4 + colw];

    if (s > 0) {
      if (wv == 0) {
        const unsigned long long* src = hg + ((s - 1) & 1) * HID + l * 8;
        unsigned long long pv[8];
        if (!dead) {
          int tries = 0;
          for (;;) {
            unsigned tmin = 0xFFFFFFFFu;
#pragma unroll
            for (int j = 0; j < 8; ++j) {
              pv[j] = __hip_atomic_load(src + j, __ATOMIC_RELAXED,
                                        __HIP_MEMORY_SCOPE_AGENT);
              tmin = min(tmin, (unsigned)(pv[j] >> 32));
            }
            if (__all((int)(tmin >= (unsigned)s))) break;
            if (++tries > DATA_SPIN) { dead = true; break; }
            __builtin_amdgcn_s_sleep(2);
          }
        }
        if (dead) {
#pragma unroll
          for (int j = 0; j < 8; ++j) pv[j] = 0ull;
        }
        const int pp = 8 * l + 4 * (l >> 4);
#pragma unroll
        for (int j = 0; j < 8; ++j) sm.hl[pp + j] = __uint_as_float((unsigned)pv[j]);
      }
      __syncthreads();
    }

    float a0 = 0.f, a1 = 0.f, a2 = 0.f, a3 = 0.f;
    const float* hseg = &sm.hl[132 * qt];
#pragma unroll
    for (int j4 = 0; j4 < 32; ++j4) {
      float4 wv4 = sm.w4[wv][j4][l];
      float4 hv4 = *reinterpret_cast<const float4*>(&hseg[4 * j4]);
      a0 = fmaf(wv4.x, hv4.x, a0);
      a1 = fmaf(wv4.y, hv4.y, a1);
      a2 = fmaf(wv4.z, hv4.z, a2);
      a3 = fmaf(wv4.w, hv4.w, a3);
    }
    float acc = (a0 + a1) + (a2 + a3);
    acc += __shfl_xor(acc, 1);
    acc += __shfl_xor(acc, 2);
    float full = acc + pre_v;

    int gbase = (l & 48) | (l & 3);
    float vi = __shfl(full, gbase);
    float vf = __shfl(full, gbase | 4);
    float vg = __shfl(full, gbase | 8);
    float vo = __shfl(full, gbase | 12);

    float si = 1.f / (1.f + __expf(-vi));
    float sf = 1.f / (1.f + __expf(-vf));
    float so = 1.f / (1.f + __expf(-vo));
    creg = sf * creg + si * tanhf(vg);
    float h = so * tanhf(creg);

    if ((l & 15) == 0) {
      int dim = d0w + (l >> 4);
      hs[(size_t)s * HID + dim] = h;
      unsigned long long pvs =
          ((unsigned long long)(unsigned)(s + 1) << 32) | (unsigned)__float_as_uint(h);
      __hip_atomic_store(hg + (s & 1) * HID + dim, pvs, __ATOMIC_RELAXED,
                         __HIP_MEMORY_SCOPE_AGENT);
    }
  }
}

__global__ __launch_bounds__(256, 1)
void lstm_scan_kernel(const float* __restrict__ pre, const float* __restrict__ Wh,
                      float* __restrict__ hs, unsigned long long* hg, int T) {
  __shared__ ScanSmem sm;
  scan_body(sm, pre, Wh, hs, hg, T);
}

// fused: blocks 0..NBLK-1 run the scan (dispatched first -> co-resident, 1
// block/CU via 133KB LDS); remaining blocks run up to two independent GEMMs
// on the other ~224 CUs. GEMM buffers are disjoint from scan buffers.
union FusedSmem {
  ScanSmem s;
  struct { __align__(16) float As[16][68]; __align__(16) float Bs[16][64]; } g;
};

__global__ __launch_bounds__(256, 1)
void scan_fused_kernel(const float* __restrict__ pre, const float* __restrict__ Wh,
                       float* __restrict__ hs, unsigned long long* hg, int T,
                       GemmDesc g1, GemmDesc g2) {
  __shared__ FusedSmem sm;
  if (blockIdx.x < NBLK) {
    scan_body(sm.s, pre, Wh, hs, hg, T);
    return;
  }
  int bx = blockIdx.x - NBLK;
  if (bx < g1.ntot) {
    gemm_tile(sm.g.As, sm.g.Bs, g1, bx);
  } else if (bx - g1.ntot < g2.ntot) {
    gemm_tile(sm.g.As, sm.g.Bs, g2, bx - g1.ntot);
  }
}

// ----------------------------------------------------------------------------
// argmax over 151 logits per row (first-occurrence semantics), one wave per row
// ----------------------------------------------------------------------------
__global__ void argmax_kernel(const float* __restrict__ dists, int* __restrict__ pred_i,
                              float* __restrict__ pred_f) {
  int r = blockIdx.x;
  int lane = threadIdx.x;
  float bv = -3.4e38f;
  int bi = NUM_CLASSES;
  for (int cc = lane; cc < NUM_CLASSES; cc += 64) {
    float v = dists[(size_t)r * NUM_CLASSES + cc];
    if (v > bv) { bv = v; bi = cc; }
  }
  for (int off = 32; off; off >>= 1) {
    float ov = __shfl_xor(bv, off);
    int oi = __shfl_xor(bi, off);
    if (ov > bv || (ov == bv && oi < bi)) { bv = ov; bi = oi; }
  }
  if (lane == 0) {
    pred_i[r] = bi;
    pred_f[r] = (float)bi;
  }
}

// ----------------------------------------------------------------------------
extern "C" void kernel_launch(void* const* d_in, const int* in_sizes, int n_in,
                              void* d_out, int out_size, void* d_ws, size_t ws_size,
                              hipStream_t stream) {
  const float* x        = (const float*)d_in[0];
  const float* odists   = (const float*)d_in[1];
  const float* box      = (const float*)d_in[2];
  const float* vobj     = (const float*)d_in[3];
  const float* vedge    = (const float*)d_in[4];
  const float* embed1   = (const float*)d_in[5];
  const float* embed2   = (const float*)d_in[6];
  const float* pos_W1   = (const float*)d_in[7];
  const float* pos_b1   = (const float*)d_in[8];
  const float* bn_gamma = (const float*)d_in[9];
  const float* bn_beta  = (const float*)d_in[10];
  const float* bn_mean  = (const float*)d_in[11];
  const float* bn_var   = (const float*)d_in[12];
  const float* pos_W2   = (const float*)d_in[13];
  const float* pos_b2   = (const float*)d_in[14];
  const float* obj_Wi   = (const float*)d_in[15];
  const float* obj_Wh   = (const float*)d_in[16];
  const float* obj_b    = (const float*)d_in[17];
  const float* dec_Wi   = (const float*)d_in[18];
  const float* dec_Wh   = (const float*)d_in[19];
  const float* dec_b    = (const float*)d_in[20];
  const float* out_W    = (const float*)d_in[21];
  const float* out_b    = (const float*)d_in[22];
  const float* edge_Wi  = (const float*)d_in[23];
  const float* edge_Wh  = (const float*)d_in[24];
  const float* edge_b   = (const float*)d_in[25];

  float* out = (float*)d_out;

  // workspace layout
  float* bigA = (float*)d_ws;                           // feats; later epre (aliased)
  float* pre0 = bigA + (size_t)N_TOT * EDGE_IN;         // 2064x2048
  float* enc  = pre0 + (size_t)N_TOT * G4;              // 2064x512
  float* dech = enc + (size_t)N_TOT * HID;              // 2064x512 (also edgeh)
  int* pred_i = (int*)(dech + (size_t)N_TOT * HID);     // 2048
  unsigned long long* hg3 = (unsigned long long*)(pred_i + N_OBJ);  // 3x1024 pairs
  float* pre1 = (float*)(hg3 + 3 * 2 * HID);            // optional 2064x2048
  float* epre = bigA;                                   // 2064x2048 (bigA dead by then)

  const size_t base_bytes =
      ((size_t)N_TOT * EDGE_IN + (size_t)N_TOT * G4 + 2 * (size_t)N_TOT * HID) * 4 +
      (size_t)N_OBJ * 4 + 3 * 2 * HID * 8 + 256;
  const size_t big_bytes = base_bytes + (size_t)N_TOT * G4 * 4;
  if (ws_size < base_bytes) return;  // fail loudly, don't corrupt
  const bool overlap = (ws_size >= big_bytes);
  float* dpre = overlap ? pre1 : pre0;  // decoder pre buffer

  const size_t OUT_PRED = (size_t)N_OBJ * NUM_CLASSES;  // 309248
  const size_t OUT_EDGE = OUT_PRED + N_OBJ;             // 311296

  init_sync_kernel<<<8, 256, 0, stream>>>((unsigned*)hg3, 3 * 2 * HID * 2);

  // build feats in bigA
  copy_x_kernel<<<(N_OBJ * (OBJ_DIM / 4) + 255) / 256, 256, 0, stream>>>(x, bigA);
  {
    long n4 = (long)16 * OBJ_IN / 4;
    copy4_kernel<<<(unsigned)((n4 + 255) / 256), 256, 0, stream>>>(
        (const float4*)vobj, (float4*)(bigA + (size_t)N_OBJ * OBJ_IN), n4);
  }
  obj_embed_kernel<<<N_OBJ, 256, 0, stream>>>(odists, embed1, bigA);
  pos_kernel<<<N_OBJ, 128, 0, stream>>>(box, pos_W1, pos_b1, bn_gamma, bn_beta, bn_mean,
                                        bn_var, pos_W2, pos_b2, bigA);

  // encoder pre (critical path)
  gemm_kernel<0><<<dim3(32, 33), 256, 0, stream>>>(bigA, OBJ_IN, obj_Wi, G4, obj_b,
                                                   pre0, G4, N_TOT, G4, OBJ_IN);

  GemmDesc gz{};  // empty descriptor (ntot=0)

  // encoder scan; overlap: dec_preA = feats @ dec_Wi -> dpre
  if (overlap) {
    GemmDesc gA{bigA, dec_Wi, dec_b, dpre, OBJ_IN, G4, G4, N_TOT, G4, OBJ_IN, 0, 32, 1056};
    scan_fused_kernel<<<NBLK + 1056, 256, 0, stream>>>(pre0, obj_Wh, enc,
                                                       hg3 + 0 * 2 * HID, N_TOT, gA, gz);
  } else {
    lstm_scan_kernel<<<NBLK, 256, 0, stream>>>(pre0, obj_Wh, enc, hg3 + 0 * 2 * HID, N_TOT);
    gemm_kernel<0><<<dim3(32, 33), 256, 0, stream>>>(bigA, OBJ_IN, dec_Wi, G4, dec_b,
                                                     dpre, G4, N_TOT, G4, OBJ_IN);
  }

  // dec_preC: + enc @ dec_Wi[4424:] (critical, small)
  gemm_kernel<1><<<dim3(32, 33), 256, 0, stream>>>(enc, HID, dec_Wi + (size_t)OBJ_IN * G4, G4,
                                                   nullptr, dpre, G4, N_TOT, G4, HID);

  // decoder scan; overlap: edge_preB = x @ edge_Wi[200:4296] -> epre (rows<2048, +bias)
  //                        edge_preV = vedge @ edge_Wi (rows 2048+, +bias)
  // (epre aliases bigA: feats fully consumed by the previous dispatches)
  {
    GemmDesc gB{x, edge_Wi + (size_t)200 * G4, edge_b, epre,
                OBJ_DIM, G4, G4, N_OBJ, G4, OBJ_DIM, 0, 32, 1024};
    GemmDesc gV{vedge, edge_Wi, edge_b, epre + (size_t)N_OBJ * G4,
                EDGE_IN, G4, G4, N_TOT - N_OBJ, G4, EDGE_IN, 0, 32, 32};
    if (overlap) {
      scan_fused_kernel<<<NBLK + 1056, 256, 0, stream>>>(dpre, dec_Wh, dech,
                                                         hg3 + 1 * 2 * HID, N_TOT, gB, gV);
    } else {
      lstm_scan_kernel<<<NBLK, 256, 0, stream>>>(dpre, dec_Wh, dech, hg3 + 1 * 2 * HID, N_TOT);
      gemm_kernel<0><<<dim3(32, 32), 256, 0, stream>>>(x, OBJ_DIM, edge_Wi + (size_t)200 * G4,
                                                       G4, edge_b, epre, G4, N_OBJ, G4, OBJ_DIM);
      gemm_kernel<0><<<dim3(32, 1), 256, 0, stream>>>(vedge, EDGE_IN, edge_Wi, G4, edge_b,
                                                      epre + (size_t)N_OBJ * G4, G4,
                                                      N_TOT - N_OBJ, G4, EDGE_IN);
    }
  }

  // edge_preC: + enc @ edge_Wi[4296:] (rows < 2048)
  gemm_kernel<1><<<dim3(32, 32), 256, 0, stream>>>(enc, HID, edge_Wi + (size_t)4296 * G4, G4,
                                                   nullptr, epre, G4, N_OBJ, G4, HID);
  // logits -> d_out, then argmax
  gemm_kernel<0><<<dim3(3, 32), 256, 0, stream>>>(dech, HID, out_W, NUM_CLASSES, out_b,
                                                  out, NUM_CLASSES, N_OBJ, NUM_CLASSES, HID);
  argmax_kernel<<<N_OBJ, 64, 0, stream>>>(out, pred_i, out + OUT_PRED);

  // edge_preA: + embed2[pred] @ edge_Wi[0:200] (rows < 2048)
  gemm_gather_kernel<<<dim3(32, 32), 256, 0, stream>>>(embed2, pred_i, edge_Wi, epre,
                                                       N_OBJ, G4, EMBED);

  // edge scan (no partner work left) — output into dech (edgeh alias)
  lstm_scan_kernel<<<NBLK, 256, 0, stream>>>(epre, edge_Wh, dech, hg3 + 2 * 2 * HID, N_TOT);

  // edge_ctx = edgeh[:2048] -> d_out
  copy4_kernel<<<1024, 256, 0, stream>>>((const float4*)dech, (float4*)(out + OUT_EDGE),
                                         (long)N_OBJ * HID / 4);
}

// Round 13
// 21822.667 us; speedup vs baseline: 1.1261x; 1.1261x over previous
//
#include <hip/hip_runtime.h>
#include <cstdint>
#include <cstddef>

#define N_OBJ 2048
#define N_TOT 2064
#define NUM_CLASSES 151
#define EMBED 200
#define HID 512
#define OBJ_DIM 4096
#define POS 128
#define OBJ_IN 4424   // 4096+200+128
#define DEC_IN 4936   // 512+4424
#define EDGE_IN 4808  // 200+4096+512
#define G4 2048       // 4*HID
#define NBLK 32       // scan blocks; 4 waves each; block owns 16 h-dims
#define DATA_SPIN 8000

// ----------------------------------------------------------------------------
// utility kernels
// ----------------------------------------------------------------------------
__global__ void init_sync_kernel(unsigned* p, int n) {
  int i = blockIdx.x * blockDim.x + threadIdx.x;
  int stride = gridDim.x * blockDim.x;
  for (; i < n; i += stride) p[i] = 0u;
}

__global__ void copy4_kernel(const float4* __restrict__ src, float4* __restrict__ dst, long n4) {
  long i = blockIdx.x * (long)blockDim.x + threadIdx.x;
  long stride = (long)gridDim.x * blockDim.x;
  for (; i < n4; i += stride) dst[i] = src[i];
}

// feats[r][0:4096] = x[r]
__global__ void copy_x_kernel(const float* __restrict__ x, float* __restrict__ feats) {
  long i = blockIdx.x * (long)blockDim.x + threadIdx.x; // over 2048*1024 float4
  if (i >= (long)N_OBJ * (OBJ_DIM / 4)) return;
  long r = i >> 10, c = i & 1023;
  reinterpret_cast<float4*>(feats + r * (long)OBJ_IN)[c] =
      reinterpret_cast<const float4*>(x + r * (long)OBJ_DIM)[c];
}

// feats[r][4096:4296] = obj_dists_in[r] @ embed1
__global__ void obj_embed_kernel(const float* __restrict__ dists,
                                 const float* __restrict__ embed1,
                                 float* __restrict__ feats) {
  int r = blockIdx.x;
  __shared__ float drow[NUM_CLASSES];
  for (int c = threadIdx.x; c < NUM_CLASSES; c += blockDim.x)
    drow[c] = dists[(size_t)r * NUM_CLASSES + c];
  __syncthreads();
  for (int j = threadIdx.x; j < EMBED; j += blockDim.x) {
    float s = 0.f;
    for (int k = 0; k < NUM_CLASSES; ++k)
      s = fmaf(drow[k], embed1[(size_t)k * EMBED + j], s);
    feats[(size_t)r * OBJ_IN + OBJ_DIM + j] = s;
  }
}

// feats[r][4296:4424] = relu(BN(box@W1+b1)@W2+b2)
__global__ void pos_kernel(const float* __restrict__ box,
                           const float* __restrict__ W1, const float* __restrict__ b1,
                           const float* __restrict__ gamma, const float* __restrict__ beta,
                           const float* __restrict__ mean, const float* __restrict__ var,
                           const float* __restrict__ W2, const float* __restrict__ b2,
                           float* __restrict__ feats) {
  int r = blockIdx.x;
  __shared__ float h[32];
  __shared__ float bx[9];
  if (threadIdx.x < 9) bx[threadIdx.x] = box[(size_t)r * 9 + threadIdx.x];
  __syncthreads();
  if (threadIdx.x < 32) {
    float s = b1[threadIdx.x];
    for (int k = 0; k < 9; ++k) s = fmaf(bx[k], W1[k * 32 + threadIdx.x], s);
    s = (s - mean[threadIdx.x]) * (1.f / sqrtf(var[threadIdx.x] + 1e-5f)) * gamma[threadIdx.x]
        + beta[threadIdx.x];
    h[threadIdx.x] = s;
  }
  __syncthreads();
  int j = threadIdx.x;
  if (j < POS) {
    float s = b2[j];
    for (int k = 0; k < 32; ++k) s = fmaf(h[k], W2[k * POS + j], s);
    feats[(size_t)r * OBJ_IN + OBJ_DIM + EMBED + j] = fmaxf(s, 0.f);
  }
}

// ----------------------------------------------------------------------------
// 64x64 GEMM (small problems): C = A@B (+bias | +=). 256 thr, 4x4/thread.
// ----------------------------------------------------------------------------
template <int ACC>
__global__ __launch_bounds__(256)
void gemm_kernel(const float* __restrict__ A, int lda,
                 const float* __restrict__ B, int ldb,
                 const float* __restrict__ bias,
                 float* __restrict__ C, int ldc,
                 int M, int N, int K) {
  __shared__ __align__(16) float As[16][68];
  __shared__ __align__(16) float Bs[16][64];
  const int row0 = blockIdx.y * 64;
  const int col0 = blockIdx.x * 64;
  const int tid = threadIdx.x;
  const int tx = tid & 15, ty = tid >> 4;
  float acc[4][4] = {};

  for (int k0 = 0; k0 < K; k0 += 16) {
#pragma unroll
    for (int l = 0; l < 4; ++l) {
      int idx = tid + l * 256;
      int m = idx >> 4, kk = idx & 15;
      int gm = row0 + m, gk = k0 + kk;
      As[kk][m] = (gm < M && gk < K) ? A[(size_t)gm * lda + gk] : 0.f;
    }
#pragma unroll
    for (int l = 0; l < 4; ++l) {
      int idx = tid + l * 256;
      int kk = idx >> 6, n = idx & 63;
      int gk = k0 + kk, gn = col0 + n;
      Bs[kk][n] = (gk < K && gn < N) ? B[(size_t)gk * ldb + gn] : 0.f;
    }
    __syncthreads();
#pragma unroll
    for (int kk = 0; kk < 16; ++kk) {
      float4 a = *reinterpret_cast<const float4*>(&As[kk][ty * 4]);
      float4 b = *reinterpret_cast<const float4*>(&Bs[kk][tx * 4]);
      acc[0][0] = fmaf(a.x, b.x, acc[0][0]); acc[0][1] = fmaf(a.x, b.y, acc[0][1]);
      acc[0][2] = fmaf(a.x, b.z, acc[0][2]); acc[0][3] = fmaf(a.x, b.w, acc[0][3]);
      acc[1][0] = fmaf(a.y, b.x, acc[1][0]); acc[1][1] = fmaf(a.y, b.y, acc[1][1]);
      acc[1][2] = fmaf(a.y, b.z, acc[1][2]); acc[1][3] = fmaf(a.y, b.w, acc[1][3]);
      acc[2][0] = fmaf(a.z, b.x, acc[2][0]); acc[2][1] = fmaf(a.z, b.y, acc[2][1]);
      acc[2][2] = fmaf(a.z, b.z, acc[2][2]); acc[2][3] = fmaf(a.z, b.w, acc[2][3]);
      acc[3][0] = fmaf(a.w, b.x, acc[3][0]); acc[3][1] = fmaf(a.w, b.y, acc[3][1]);
      acc[3][2] = fmaf(a.w, b.z, acc[3][2]); acc[3][3] = fmaf(a.w, b.w, acc[3][3]);
    }
    __syncthreads();
  }
#pragma unroll
  for (int i = 0; i < 4; ++i) {
    int gm = row0 + ty * 4 + i;
    if (gm >= M) continue;
#pragma unroll
    for (int j = 0; j < 4; ++j) {
      int gn = col0 + tx * 4 + j;
      if (gn >= N) continue;
      size_t o = (size_t)gm * ldc + gn;
      if (ACC) C[o] += acc[i][j];
      else C[o] = acc[i][j] + (bias ? bias[gn] : 0.f);
    }
  }
}

// ----------------------------------------------------------------------------
// 128x64 GEMM (large problems): 256 thr, 8x4/thread — 2x arithmetic intensity
// per LDS read vs 64x64; As reads are 16-lane broadcasts (conflict-free).
// ----------------------------------------------------------------------------
template <int ACC>
__global__ __launch_bounds__(256)
void gemm128_kernel(const float* __restrict__ A, int lda,
                    const float* __restrict__ B, int ldb,
                    const float* __restrict__ bias,
                    float* __restrict__ C, int ldc,
                    int M, int N, int K) {
  __shared__ __align__(16) float As[16][132];
  __shared__ __align__(16) float Bs[16][64];
  const int row0 = blockIdx.y * 128;
  const int col0 = blockIdx.x * 64;
  const int tid = threadIdx.x;
  const int tx = tid & 15, ty = tid >> 4;  // ty 0..15
  float acc[8][4] = {};

  for (int k0 = 0; k0 < K; k0 += 16) {
#pragma unroll
    for (int l = 0; l < 8; ++l) {
      int idx = tid + l * 256;
      int m = idx >> 4, kk = idx & 15;
      int gm = row0 + m, gk = k0 + kk;
      As[kk][m] = (gm < M && gk < K) ? A[(size_t)gm * lda + gk] : 0.f;
    }
#pragma unroll
    for (int l = 0; l < 4; ++l) {
      int idx = tid + l * 256;
      int kk = idx >> 6, n = idx & 63;
      int gk = k0 + kk, gn = col0 + n;
      Bs[kk][n] = (gk < K && gn < N) ? B[(size_t)gk * ldb + gn] : 0.f;
    }
    __syncthreads();
#pragma unroll
    for (int kk = 0; kk < 16; ++kk) {
      float4 a0 = *reinterpret_cast<const float4*>(&As[kk][ty * 8]);
      float4 a1 = *reinterpret_cast<const float4*>(&As[kk][ty * 8 + 4]);
      float4 b = *reinterpret_cast<const float4*>(&Bs[kk][tx * 4]);
      acc[0][0] = fmaf(a0.x, b.x, acc[0][0]); acc[0][1] = fmaf(a0.x, b.y, acc[0][1]);
      acc[0][2] = fmaf(a0.x, b.z, acc[0][2]); acc[0][3] = fmaf(a0.x, b.w, acc[0][3]);
      acc[1][0] = fmaf(a0.y, b.x, acc[1][0]); acc[1][1] = fmaf(a0.y, b.y, acc[1][1]);
      acc[1][2] = fmaf(a0.y, b.z, acc[1][2]); acc[1][3] = fmaf(a0.y, b.w, acc[1][3]);
      acc[2][0] = fmaf(a0.z, b.x, acc[2][0]); acc[2][1] = fmaf(a0.z, b.y, acc[2][1]);
      acc[2][2] = fmaf(a0.z, b.z, acc[2][2]); acc[2][3] = fmaf(a0.z, b.w, acc[2][3]);
      acc[3][0] = fmaf(a0.w, b.x, acc[3][0]); acc[3][1] = fmaf(a0.w, b.y, acc[3][1]);
      acc[3][2] = fmaf(a0.w, b.z, acc[3][2]); acc[3][3] = fmaf(a0.w, b.w, acc[3][3]);
      acc[4][0] = fmaf(a1.x, b.x, acc[4][0]); acc[4][1] = fmaf(a1.x, b.y, acc[4][1]);
      acc[4][2] = fmaf(a1.x, b.z, acc[4][2]); acc[4][3] = fmaf(a1.x, b.w, acc[4][3]);
      acc[5][0] = fmaf(a1.y, b.x, acc[5][0]); acc[5][1] = fmaf(a1.y, b.y, acc[5][1]);
      acc[5][2] = fmaf(a1.y, b.z, acc[5][2]); acc[5][3] = fmaf(a1.y, b.w, acc[5][3]);
      acc[6][0] = fmaf(a1.z, b.x, acc[6][0]); acc[6][1] = fmaf(a1.z, b.y, acc[6][1]);
      acc[6][2] = fmaf(a1.z, b.z, acc[6][2]); acc[6][3] = fmaf(a1.z, b.w, acc[6][3]);
      acc[7][0] = fmaf(a1.w, b.x, acc[7][0]); acc[7][1] = fmaf(a1.w, b.y, acc[7][1]);
      acc[7][2] = fmaf(a1.w, b.z, acc[7][2]); acc[7][3] = fmaf(a1.w, b.w, acc[7][3]);
    }
    __syncthreads();
  }
#pragma unroll
  for (int i = 0; i < 8; ++i) {
    int gm = row0 + ty * 8 + i;
    if (gm >= M) continue;
#pragma unroll
    for (int j = 0; j < 4; ++j) {
      int gn = col0 + tx * 4 + j;
      if (gn >= N) continue;
      size_t o = (size_t)gm * ldc + gn;
      if (ACC) C[o] += acc[i][j];
      else C[o] = acc[i][j] + (bias ? bias[gn] : 0.f);
    }
  }
}

// epre[r] += embed2[pred[r]] @ B   (M=2048, K=EMBED, acc into ldc=G4)
__global__ __launch_bounds__(256)
void gemm_gather_kernel(const float* __restrict__ embed2, const int* __restrict__ pred,
                        const float* __restrict__ B, float* __restrict__ C,
                        int M, int N, int K) {
  __shared__ __align__(16) float As[16][68];
  __shared__ __align__(16) float Bs[16][64];
  const int row0 = blockIdx.y * 64, col0 = blockIdx.x * 64;
  const int tid = threadIdx.x;
  const int tx = tid & 15, ty = tid >> 4;
  float acc[4][4] = {};
  for (int k0 = 0; k0 < K; k0 += 16) {
#pragma unroll
    for (int l = 0; l < 4; ++l) {
      int idx = tid + l * 256;
      int m = idx >> 4, kk = idx & 15;
      int gm = row0 + m, gk = k0 + kk;
      As[kk][m] = (gm < M && gk < K) ? embed2[(size_t)pred[gm] * EMBED + gk] : 0.f;
    }
#pragma unroll
    for (int l = 0; l < 4; ++l) {
      int idx = tid + l * 256;
      int kk = idx >> 6, n = idx & 63;
      int gk = k0 + kk, gn = col0 + n;
      Bs[kk][n] = (gk < K && gn < N) ? B[(size_t)gk * G4 + gn] : 0.f;
    }
    __syncthreads();
#pragma unroll
    for (int kk = 0; kk < 16; ++kk) {
      float4 a = *reinterpret_cast<const float4*>(&As[kk][ty * 4]);
      float4 b = *reinterpret_cast<const float4*>(&Bs[kk][tx * 4]);
      acc[0][0] = fmaf(a.x, b.x, acc[0][0]); acc[0][1] = fmaf(a.x, b.y, acc[0][1]);
      acc[0][2] = fmaf(a.x, b.z, acc[0][2]); acc[0][3] = fmaf(a.x, b.w, acc[0][3]);
      acc[1][0] = fmaf(a.y, b.x, acc[1][0]); acc[1][1] = fmaf(a.y, b.y, acc[1][1]);
      acc[1][2] = fmaf(a.y, b.z, acc[1][2]); acc[1][3] = fmaf(a.y, b.w, acc[1][3]);
      acc[2][0] = fmaf(a.z, b.x, acc[2][0]); acc[2][1] = fmaf(a.z, b.y, acc[2][1]);
      acc[2][2] = fmaf(a.z, b.z, acc[2][2]); acc[2][3] = fmaf(a.z, b.w, acc[2][3]);
      acc[3][0] = fmaf(a.w, b.x, acc[3][0]); acc[3][1] = fmaf(a.w, b.y, acc[3][1]);
      acc[3][2] = fmaf(a.w, b.z, acc[3][2]); acc[3][3] = fmaf(a.w, b.w, acc[3][3]);
    }
    __syncthreads();
  }
#pragma unroll
  for (int i = 0; i < 4; ++i) {
    int gm = row0 + ty * 4 + i;
    if (gm >= M) continue;
#pragma unroll
    for (int j = 0; j < 4; ++j) {
      int gn = col0 + tx * 4 + j;
      if (gn >= N) continue;
      C[(size_t)gm * G4 + gn] += acc[i][j];
    }
  }
}

// ----------------------------------------------------------------------------
// persistent LSTM scan — BYTE-IDENTICAL logic to the R11-proven kernel.
// 32 blocks x 4 waves; tagged-pair exchange {tag=s+1, h} via relaxed/agent
// atomics; wave0 single-poller with s_sleep(2) backoff; bounded + sticky
// dead-latch (worst case loud absmax fail, never a hang).
// R12 lesson: do NOT co-schedule GEMM work with this kernel — background
// memory traffic inflates the coherence-point RTT by ~34%.
// ----------------------------------------------------------------------------
__global__ __launch_bounds__(256, 1)
void lstm_scan_kernel(const float* __restrict__ pre,      // T x 2048
                      const float* __restrict__ Wh,       // 512 x 2048
                      float* __restrict__ hs,             // T x 512
                      unsigned long long* hg,             // 2*512 tagged pairs
                      int T) {
  __shared__ float4 w4[4][32][64];               // 128 KB: per-wave [k4][lane]
  __shared__ float hl[532];                      // block-shared h, 4x(128+4 pad)

  const int tid = threadIdx.x;
  const int wv = tid >> 6;                       // wave 0..3
  const int l = tid & 63;

  const int q = l >> 2;                          // col within wave, 0..15
  const int qt = l & 3;                          // k-quarter (128 k each)
  const int dq = q >> 2;                         // dim within wave, 0..3
  const int gq = q & 3;                          // gate (i,f,g,o)
  const int d0w = blockIdx.x * 16 + wv * 4;      // wave's first dim
  const int colw = gq * HID + d0w + dq;          // Wh column

  // stage this wave's 16 columns into LDS (once)
  {
    const float* base = Wh + (size_t)(qt * 128) * G4 + colw;
#pragma unroll 4
    for (int j4 = 0; j4 < 32; ++j4) {
      float4 t;
      t.x = base[(size_t)(4 * j4 + 0) * G4];
      t.y = base[(size_t)(4 * j4 + 1) * G4];
      t.z = base[(size_t)(4 * j4 + 2) * G4];
      t.w = base[(size_t)(4 * j4 + 3) * G4];
      w4[wv][j4][l] = t;
    }
  }
  for (int i = tid; i < 532; i += 256) hl[i] = 0.f;  // h_{-1} = 0
  __syncthreads();

  float creg = 0.f;
  bool dead = false;  // wave-0 only (uniform there); STICKY

  for (int s = 0; s < T; ++s) {
    // independent of h: prefetch pre-activation (overlaps poll/barrier)
    float pre_v = pre[(size_t)s * G4 + colw];

    if (s > 0) {
      if (wv == 0) {
        // poll the tagged pairs of buffer (s-1)&1: lane l owns dims [8l,8l+8)
        const unsigned long long* src = hg + ((s - 1) & 1) * HID + l * 8;
        unsigned long long pv[8];
        if (!dead) {
          int tries = 0;
          for (;;) {
            unsigned tmin = 0xFFFFFFFFu;
#pragma unroll
            for (int j = 0; j < 8; ++j) {
              pv[j] = __hip_atomic_load(src + j, __ATOMIC_RELAXED,
                                        __HIP_MEMORY_SCOPE_AGENT);
              tmin = min(tmin, (unsigned)(pv[j] >> 32));
            }
            if (__all((int)(tmin >= (unsigned)s))) break;  // snapshot valid
            if (++tries > DATA_SPIN) { dead = true; break; }
            __builtin_amdgcn_s_sleep(2);  // keep the fabric quiet
          }
        }
        if (dead) {
#pragma unroll
          for (int j = 0; j < 8; ++j) pv[j] = 0ull;
        }
        const int pp = 8 * l + 4 * (l >> 4);  // +4 pad per 128-segment
#pragma unroll
        for (int j = 0; j < 8; ++j) hl[pp + j] = __uint_as_float((unsigned)pv[j]);
      }
      __syncthreads();  // waves 1-3 wait here (no traffic); hl now valid
    }

    // dot: this lane's k-quarter of its column (4 indep FMA chains)
    float a0 = 0.f, a1 = 0.f, a2 = 0.f, a3 = 0.f;
    const float* hseg = &hl[132 * qt];
#pragma unroll
    for (int j4 = 0; j4 < 32; ++j4) {
      float4 wv4 = w4[wv][j4][l];
      float4 hv4 = *reinterpret_cast<const float4*>(&hseg[4 * j4]);
      a0 = fmaf(wv4.x, hv4.x, a0);
      a1 = fmaf(wv4.y, hv4.y, a1);
      a2 = fmaf(wv4.z, hv4.z, a2);
      a3 = fmaf(wv4.w, hv4.w, a3);
    }
    float acc = (a0 + a1) + (a2 + a3);
    acc += __shfl_xor(acc, 1);
    acc += __shfl_xor(acc, 2);
    float full = acc + pre_v;

    // gather the 4 gate values for this lane's dim (16-lane group)
    int gbase = (l & 48) | (l & 3);
    float vi = __shfl(full, gbase);
    float vf = __shfl(full, gbase | 4);
    float vg = __shfl(full, gbase | 8);
    float vo = __shfl(full, gbase | 12);

    float si = 1.f / (1.f + __expf(-vi));
    float sf = 1.f / (1.f + __expf(-vf));
    float so = 1.f / (1.f + __expf(-vo));
    creg = sf * creg + si * tanhf(vg);
    float h = so * tanhf(creg);

    if ((l & 15) == 0) {
      int dim = d0w + (l >> 4);
      hs[(size_t)s * HID + dim] = h;
      unsigned long long pvs =
          ((unsigned long long)(unsigned)(s + 1) << 32) | (unsigned)__float_as_uint(h);
      __hip_atomic_store(hg + (s & 1) * HID + dim, pvs, __ATOMIC_RELAXED,
                         __HIP_MEMORY_SCOPE_AGENT);  // fire-and-forget: tag IS the flag
    }
  }
}

// ----------------------------------------------------------------------------
// argmax over 151 logits per row (first-occurrence semantics), one wave per row
// ----------------------------------------------------------------------------
__global__ void argmax_kernel(const float* __restrict__ dists, int* __restrict__ pred_i,
                              float* __restrict__ pred_f) {
  int r = blockIdx.x;
  int lane = threadIdx.x;
  float bv = -3.4e38f;
  int bi = NUM_CLASSES;
  for (int cc = lane; cc < NUM_CLASSES; cc += 64) {
    float v = dists[(size_t)r * NUM_CLASSES + cc];
    if (v > bv) { bv = v; bi = cc; }
  }
  for (int off = 32; off; off >>= 1) {
    float ov = __shfl_xor(bv, off);
    int oi = __shfl_xor(bi, off);
    if (ov > bv || (ov == bv && oi < bi)) { bv = ov; bi = oi; }
  }
  if (lane == 0) {
    pred_i[r] = bi;
    pred_f[r] = (float)bi;
  }
}

// ----------------------------------------------------------------------------
extern "C" void kernel_launch(void* const* d_in, const int* in_sizes, int n_in,
                              void* d_out, int out_size, void* d_ws, size_t ws_size,
                              hipStream_t stream) {
  const float* x        = (const float*)d_in[0];
  const float* odists   = (const float*)d_in[1];
  const float* box      = (const float*)d_in[2];
  const float* vobj     = (const float*)d_in[3];
  const float* vedge    = (const float*)d_in[4];
  const float* embed1   = (const float*)d_in[5];
  const float* embed2   = (const float*)d_in[6];
  const float* pos_W1   = (const float*)d_in[7];
  const float* pos_b1   = (const float*)d_in[8];
  const float* bn_gamma = (const float*)d_in[9];
  const float* bn_beta  = (const float*)d_in[10];
  const float* bn_mean  = (const float*)d_in[11];
  const float* bn_var   = (const float*)d_in[12];
  const float* pos_W2   = (const float*)d_in[13];
  const float* pos_b2   = (const float*)d_in[14];
  const float* obj_Wi   = (const float*)d_in[15];
  const float* obj_Wh   = (const float*)d_in[16];
  const float* obj_b    = (const float*)d_in[17];
  const float* dec_Wi   = (const float*)d_in[18];
  const float* dec_Wh   = (const float*)d_in[19];
  const float* dec_b    = (const float*)d_in[20];
  const float* out_W    = (const float*)d_in[21];
  const float* out_b    = (const float*)d_in[22];
  const float* edge_Wi  = (const float*)d_in[23];
  const float* edge_Wh  = (const float*)d_in[24];
  const float* edge_b   = (const float*)d_in[25];

  float* out = (float*)d_out;

  // workspace layout (R11-identical footprint)
  float* bigA = (float*)d_ws;                           // feats; later epre (alias)
  float* pre0 = bigA + (size_t)N_TOT * EDGE_IN;         // 2064x2048
  float* enc  = pre0 + (size_t)N_TOT * G4;              // 2064x512
  float* dech = enc + (size_t)N_TOT * HID;              // 2064x512 (also edgeh)
  int* pred_i = (int*)(dech + (size_t)N_TOT * HID);     // 2048
  unsigned long long* hg3 = (unsigned long long*)(pred_i + N_OBJ);  // 3x1024 pairs
  float* epre = bigA;                                   // 2064x2048 (feats dead by then)

  const size_t need_bytes =
      ((size_t)N_TOT * EDGE_IN + (size_t)N_TOT * G4 + 2 * (size_t)N_TOT * HID) * 4 +
      (size_t)N_OBJ * 4 + 3 * 2 * HID * 8 + 256;
  if (ws_size < need_bytes) return;  // fail loudly, don't corrupt

  const size_t OUT_PRED = (size_t)N_OBJ * NUM_CLASSES;  // 309248
  const size_t OUT_EDGE = OUT_PRED + N_OBJ;             // 311296

  init_sync_kernel<<<8, 256, 0, stream>>>((unsigned*)hg3, 3 * 2 * HID * 2);

  // build feats in bigA
  copy_x_kernel<<<(N_OBJ * (OBJ_DIM / 4) + 255) / 256, 256, 0, stream>>>(x, bigA);
  {
    long n4 = (long)16 * OBJ_IN / 4;
    copy4_kernel<<<(unsigned)((n4 + 255) / 256), 256, 0, stream>>>(
        (const float4*)vobj, (float4*)(bigA + (size_t)N_OBJ * OBJ_IN), n4);
  }
  obj_embed_kernel<<<N_OBJ, 256, 0, stream>>>(odists, embed1, bigA);
  pos_kernel<<<N_OBJ, 128, 0, stream>>>(box, pos_W1, pos_b1, bn_gamma, bn_beta, bn_mean,
                                        bn_var, pos_W2, pos_b2, bigA);

  // encoder pre + scan
  gemm128_kernel<0><<<dim3(32, 17), 256, 0, stream>>>(bigA, OBJ_IN, obj_Wi, G4, obj_b,
                                                      pre0, G4, N_TOT, G4, OBJ_IN);
  lstm_scan_kernel<<<NBLK, 256, 0, stream>>>(pre0, obj_Wh, enc, hg3 + 0 * 2 * HID, N_TOT);

  // decoder pre (two K-parts) + scan
  gemm128_kernel<0><<<dim3(32, 17), 256, 0, stream>>>(bigA, OBJ_IN, dec_Wi, G4, dec_b,
                                                      pre0, G4, N_TOT, G4, OBJ_IN);
  gemm128_kernel<1><<<dim3(32, 17), 256, 0, stream>>>(enc, HID, dec_Wi + (size_t)OBJ_IN * G4,
                                                      G4, nullptr, pre0, G4, N_TOT, G4, HID);
  lstm_scan_kernel<<<NBLK, 256, 0, stream>>>(pre0, dec_Wh, dech, hg3 + 1 * 2 * HID, N_TOT);

  // edge pre, decomposed (no edge_feats materialization):
  //   rows<2048:  epre = x @ edge_Wi[200:4296] + edge_b        (gemm128, bias)
  //               epre += enc @ edge_Wi[4296:4808]             (gemm128, acc)
  //               epre += embed2[pred] @ edge_Wi[0:200]        (gather, acc)
  //   rows 2048+: epre = vedge @ edge_Wi + edge_b              (gemm64)
  gemm128_kernel<0><<<dim3(32, 16), 256, 0, stream>>>(x, OBJ_DIM, edge_Wi + (size_t)200 * G4,
                                                      G4, edge_b, epre, G4, N_OBJ, G4, OBJ_DIM);
  gemm_kernel<0><<<dim3(32, 1), 256, 0, stream>>>(vedge, EDGE_IN, edge_Wi, G4, edge_b,
                                                  epre + (size_t)N_OBJ * G4, G4,
                                                  N_TOT - N_OBJ, G4, EDGE_IN);
  gemm128_kernel<1><<<dim3(32, 16), 256, 0, stream>>>(enc, HID, edge_Wi + (size_t)4296 * G4,
                                                      G4, nullptr, epre, G4, N_OBJ, G4, HID);

  // logits -> d_out, then argmax, then the gathered embed2 part
  gemm_kernel<0><<<dim3(3, 32), 256, 0, stream>>>(dech, HID, out_W, NUM_CLASSES, out_b,
                                                  out, NUM_CLASSES, N_OBJ, NUM_CLASSES, HID);
  argmax_kernel<<<N_OBJ, 64, 0, stream>>>(out, pred_i, out + OUT_PRED);
  gemm_gather_kernel<<<dim3(32, 32), 256, 0, stream>>>(embed2, pred_i, edge_Wi, epre,
                                                       N_OBJ, G4, EMBED);

  // edge scan -> dech (edgeh alias), then copy out
  lstm_scan_kernel<<<NBLK, 256, 0, stream>>>(epre, edge_Wh, dech, hg3 + 2 * 2 * HID, N_TOT);
  copy4_kernel<<<1024, 256, 0, stream>>>((const float4*)dech, (float4*)(out + OUT_EDGE),
                                         (long)N_OBJ * HID / 4);
}

// Round 14
// 16685.814 us; speedup vs baseline: 1.4728x; 1.3079x over previous
//
#include <hip/hip_runtime.h>
#include <cstdint>
#include <cstddef>

#define N_OBJ 2048
#define N_TOT 2064
#define NUM_CLASSES 151
#define EMBED 200
#define HID 512
#define OBJ_DIM 4096
#define POS 128
#define OBJ_IN 4424   // 4096+200+128
#define DEC_IN 4936   // 512+4424
#define EDGE_IN 4808  // 200+4096+512
#define G4 2048       // 4*HID
#define NBLK 32       // obj blocks (16 dims each); dec = 64 blocks (8 dims each)
#define NDEC 64
#define SPIN_EDGE 8000
#define SPIN_FUSED 12000

typedef unsigned long long ull;

// ----------------------------------------------------------------------------
// utility kernels
// ----------------------------------------------------------------------------
__global__ void init_sync_kernel(unsigned* p, int n) {
  int i = blockIdx.x * blockDim.x + threadIdx.x;
  int stride = gridDim.x * blockDim.x;
  for (; i < n; i += stride) p[i] = 0u;
}

__global__ void copy4_kernel(const float4* __restrict__ src, float4* __restrict__ dst, long n4) {
  long i = blockIdx.x * (long)blockDim.x + threadIdx.x;
  long stride = (long)gridDim.x * blockDim.x;
  for (; i < n4; i += stride) dst[i] = src[i];
}

// feats[r][0:4096] = x[r]
__global__ void copy_x_kernel(const float* __restrict__ x, float* __restrict__ feats) {
  long i = blockIdx.x * (long)blockDim.x + threadIdx.x;
  if (i >= (long)N_OBJ * (OBJ_DIM / 4)) return;
  long r = i >> 10, c = i & 1023;
  reinterpret_cast<float4*>(feats + r * (long)OBJ_IN)[c] =
      reinterpret_cast<const float4*>(x + r * (long)OBJ_DIM)[c];
}

// feats[r][4096:4296] = obj_dists_in[r] @ embed1
__global__ void obj_embed_kernel(const float* __restrict__ dists,
                                 const float* __restrict__ embed1,
                                 float* __restrict__ feats) {
  int r = blockIdx.x;
  __shared__ float drow[NUM_CLASSES];
  for (int c = threadIdx.x; c < NUM_CLASSES; c += blockDim.x)
    drow[c] = dists[(size_t)r * NUM_CLASSES + c];
  __syncthreads();
  for (int j = threadIdx.x; j < EMBED; j += blockDim.x) {
    float s = 0.f;
    for (int k = 0; k < NUM_CLASSES; ++k)
      s = fmaf(drow[k], embed1[(size_t)k * EMBED + j], s);
    feats[(size_t)r * OBJ_IN + OBJ_DIM + j] = s;
  }
}

// feats[r][4296:4424] = relu(BN(box@W1+b1)@W2+b2)
__global__ void pos_kernel(const float* __restrict__ box,
                           const float* __restrict__ W1, const float* __restrict__ b1,
                           const float* __restrict__ gamma, const float* __restrict__ beta,
                           const float* __restrict__ mean, const float* __restrict__ var,
                           const float* __restrict__ W2, const float* __restrict__ b2,
                           float* __restrict__ feats) {
  int r = blockIdx.x;
  __shared__ float h[32];
  __shared__ float bx[9];
  if (threadIdx.x < 9) bx[threadIdx.x] = box[(size_t)r * 9 + threadIdx.x];
  __syncthreads();
  if (threadIdx.x < 32) {
    float s = b1[threadIdx.x];
    for (int k = 0; k < 9; ++k) s = fmaf(bx[k], W1[k * 32 + threadIdx.x], s);
    s = (s - mean[threadIdx.x]) * (1.f / sqrtf(var[threadIdx.x] + 1e-5f)) * gamma[threadIdx.x]
        + beta[threadIdx.x];
    h[threadIdx.x] = s;
  }
  __syncthreads();
  int j = threadIdx.x;
  if (j < POS) {
    float s = b2[j];
    for (int k = 0; k < 32; ++k) s = fmaf(h[k], W2[k * POS + j], s);
    feats[(size_t)r * OBJ_IN + OBJ_DIM + EMBED + j] = fmaxf(s, 0.f);
  }
}

// ----------------------------------------------------------------------------
// 64x64 GEMM (R11-proven speed) with A element stride (astr): element (gm,gk)
// at A[gm*lda + gk*astr]. astr=2 reads the low floats of tagged qword arrays.
// ----------------------------------------------------------------------------
template <int ACC>
__global__ __launch_bounds__(256)
void gemm_kernel(const float* __restrict__ A, int lda, int astr,
                 const float* __restrict__ B, int ldb,
                 const float* __restrict__ bias,
                 float* __restrict__ C, int ldc,
                 int M, int N, int K) {
  __shared__ __align__(16) float As[16][68];
  __shared__ __align__(16) float Bs[16][64];
  const int row0 = blockIdx.y * 64;
  const int col0 = blockIdx.x * 64;
  const int tid = threadIdx.x;
  const int tx = tid & 15, ty = tid >> 4;
  float acc[4][4] = {};

  for (int k0 = 0; k0 < K; k0 += 16) {
#pragma unroll
    for (int l = 0; l < 4; ++l) {
      int idx = tid + l * 256;
      int m = idx >> 4, kk = idx & 15;
      int gm = row0 + m, gk = k0 + kk;
      As[kk][m] = (gm < M && gk < K) ? A[(size_t)gm * lda + (size_t)gk * astr] : 0.f;
    }
#pragma unroll
    for (int l = 0; l < 4; ++l) {
      int idx = tid + l * 256;
      int kk = idx >> 6, n = idx & 63;
      int gk = k0 + kk, gn = col0 + n;
      Bs[kk][n] = (gk < K && gn < N) ? B[(size_t)gk * ldb + gn] : 0.f;
    }
    __syncthreads();
#pragma unroll
    for (int kk = 0; kk < 16; ++kk) {
      float4 a = *reinterpret_cast<const float4*>(&As[kk][ty * 4]);
      float4 b = *reinterpret_cast<const float4*>(&Bs[kk][tx * 4]);
      acc[0][0] = fmaf(a.x, b.x, acc[0][0]); acc[0][1] = fmaf(a.x, b.y, acc[0][1]);
      acc[0][2] = fmaf(a.x, b.z, acc[0][2]); acc[0][3] = fmaf(a.x, b.w, acc[0][3]);
      acc[1][0] = fmaf(a.y, b.x, acc[1][0]); acc[1][1] = fmaf(a.y, b.y, acc[1][1]);
      acc[1][2] = fmaf(a.y, b.z, acc[1][2]); acc[1][3] = fmaf(a.y, b.w, acc[1][3]);
      acc[2][0] = fmaf(a.z, b.x, acc[2][0]); acc[2][1] = fmaf(a.z, b.y, acc[2][1]);
      acc[2][2] = fmaf(a.z, b.z, acc[2][2]); acc[2][3] = fmaf(a.z, b.w, acc[2][3]);
      acc[3][0] = fmaf(a.w, b.x, acc[3][0]); acc[3][1] = fmaf(a.w, b.y, acc[3][1]);
      acc[3][2] = fmaf(a.w, b.z, acc[3][2]); acc[3][3] = fmaf(a.w, b.w, acc[3][3]);
    }
    __syncthreads();
  }
#pragma unroll
  for (int i = 0; i < 4; ++i) {
    int gm = row0 + ty * 4 + i;
    if (gm >= M) continue;
#pragma unroll
    for (int j = 0; j < 4; ++j) {
      int gn = col0 + tx * 4 + j;
      if (gn >= N) continue;
      size_t o = (size_t)gm * ldc + gn;
      if (ACC) C[o] += acc[i][j];
      else C[o] = acc[i][j] + (bias ? bias[gn] : 0.f);
    }
  }
}

// epre[r] += embed2[pred[r]] @ B  (M=2048, K=EMBED, ldc=G4) — validated R13
__global__ __launch_bounds__(256)
void gemm_gather_kernel(const float* __restrict__ embed2, const int* __restrict__ pred,
                        const float* __restrict__ B, float* __restrict__ C,
                        int M, int N, int K) {
  __shared__ __align__(16) float As[16][68];
  __shared__ __align__(16) float Bs[16][64];
  const int row0 = blockIdx.y * 64, col0 = blockIdx.x * 64;
  const int tid = threadIdx.x;
  const int tx = tid & 15, ty = tid >> 4;
  float acc[4][4] = {};
  for (int k0 = 0; k0 < K; k0 += 16) {
#pragma unroll
    for (int l = 0; l < 4; ++l) {
      int idx = tid + l * 256;
      int m = idx >> 4, kk = idx & 15;
      int gm = row0 + m, gk = k0 + kk;
      As[kk][m] = (gm < M && gk < K) ? embed2[(size_t)pred[gm] * EMBED + gk] : 0.f;
    }
#pragma unroll
    for (int l = 0; l < 4; ++l) {
      int idx = tid + l * 256;
      int kk = idx >> 6, n = idx & 63;
      int gk = k0 + kk, gn = col0 + n;
      Bs[kk][n] = (gk < K && gn < N) ? B[(size_t)gk * G4 + gn] : 0.f;
    }
    __syncthreads();
#pragma unroll
    for (int kk = 0; kk < 16; ++kk) {
      float4 a = *reinterpret_cast<const float4*>(&As[kk][ty * 4]);
      float4 b = *reinterpret_cast<const float4*>(&Bs[kk][tx * 4]);
      acc[0][0] = fmaf(a.x, b.x, acc[0][0]); acc[0][1] = fmaf(a.x, b.y, acc[0][1]);
      acc[0][2] = fmaf(a.x, b.z, acc[0][2]); acc[0][3] = fmaf(a.x, b.w, acc[0][3]);
      acc[1][0] = fmaf(a.y, b.x, acc[1][0]); acc[1][1] = fmaf(a.y, b.y, acc[1][1]);
      acc[1][2] = fmaf(a.y, b.z, acc[1][2]); acc[1][3] = fmaf(a.y, b.w, acc[1][3]);
      acc[2][0] = fmaf(a.z, b.x, acc[2][0]); acc[2][1] = fmaf(a.z, b.y, acc[2][1]);
      acc[2][2] = fmaf(a.z, b.z, acc[2][2]); acc[2][3] = fmaf(a.z, b.w, acc[2][3]);
      acc[3][0] = fmaf(a.w, b.x, acc[3][0]); acc[3][1] = fmaf(a.w, b.y, acc[3][1]);
      acc[3][2] = fmaf(a.w, b.z, acc[3][2]); acc[3][3] = fmaf(a.w, b.w, acc[3][3]);
    }
    __syncthreads();
  }
#pragma unroll
  for (int i = 0; i < 4; ++i) {
    int gm = row0 + ty * 4 + i;
    if (gm >= M) continue;
#pragma unroll
    for (int j = 0; j < 4; ++j) {
      int gn = col0 + tx * 4 + j;
      if (gn >= N) continue;
      C[(size_t)gm * G4 + gn] += acc[i][j];
    }
  }
}

// ----------------------------------------------------------------------------
// FUSED encoder+decoder pipeline. Blocks 0..31: obj (R11-proven per-wave math,
// full-array tagged store/poll). Blocks 32..95: dec — 8 dims each, k=1024 dot
// over [dech[s-1](512) ; enc[s](512)] with [dec_Wh ; dec_Wi_enc] folded into
// LDS. Full-array exchange {tag=s+1,h} per (step,dim) slot: no ring, no lap
// hazard, no backpressure (obj may run ahead freely). Zero-init per launch.
// All atomics relaxed/agent (the only proven-safe codegen: R2/R5/R7/R11).
// Bounded spins + sticky dead-latch: worst case loud absmax fail, never hang.
// ----------------------------------------------------------------------------
__global__ __launch_bounds__(256, 1)
void fused_scan_kernel(const float* __restrict__ preO, const float* __restrict__ objWh,
                       const float* __restrict__ preD, const float* __restrict__ decWh,
                       const float* __restrict__ decWi,
                       ull* encX, ull* dechX, int T) {
  __shared__ float4 w4[4][32][64];   // 128 KB
  __shared__ float hl[1056];         // obj uses [0,532); dec uses all
  const int tid = threadIdx.x;
  const int wv = tid >> 6;
  const int l = tid & 63;

  if (blockIdx.x < NBLK) {
    // ======================= obj role (16 dims/block) =======================
    const int q = l >> 2, qt = l & 3, dq = q >> 2, gq = q & 3;
    const int d0w = blockIdx.x * 16 + wv * 4;
    const int colw = gq * HID + d0w + dq;
    {
      const float* base = objWh + (size_t)(qt * 128) * G4 + colw;
#pragma unroll 4
      for (int j4 = 0; j4 < 32; ++j4) {
        float4 t;
        t.x = base[(size_t)(4 * j4 + 0) * G4];
        t.y = base[(size_t)(4 * j4 + 1) * G4];
        t.z = base[(size_t)(4 * j4 + 2) * G4];
        t.w = base[(size_t)(4 * j4 + 3) * G4];
        w4[wv][j4][l] = t;
      }
    }
    for (int i = tid; i < 532; i += 256) hl[i] = 0.f;
    __syncthreads();

    float creg = 0.f;
    bool dead = false;
    for (int s = 0; s < T; ++s) {
      float pre_v = preO[(size_t)s * G4 + colw];
      if (s > 0) {
        if (wv == 0) {
          const ull* src = encX + (size_t)(s - 1) * HID + l * 8;
          ull pv[8];
          if (!dead) {
            int tries = 0;
            for (;;) {
              unsigned tmin = 0xFFFFFFFFu;
#pragma unroll
              for (int j = 0; j < 8; ++j) {
                pv[j] = __hip_atomic_load(src + j, __ATOMIC_RELAXED, __HIP_MEMORY_SCOPE_AGENT);
                tmin = min(tmin, (unsigned)(pv[j] >> 32));
              }
              if (__all((int)(tmin >= (unsigned)s))) break;
              if (++tries > SPIN_FUSED) { dead = true; break; }
              __builtin_amdgcn_s_sleep(2);
            }
          }
          if (dead) {
#pragma unroll
            for (int j = 0; j < 8; ++j) pv[j] = 0ull;
          }
          const int pp = 8 * l + 4 * (l >> 4);
#pragma unroll
          for (int j = 0; j < 8; ++j) hl[pp + j] = __uint_as_float((unsigned)pv[j]);
        }
        __syncthreads();
      }
      float a0 = 0.f, a1 = 0.f, a2 = 0.f, a3 = 0.f;
      const float* hseg = &hl[132 * qt];
#pragma unroll
      for (int j4 = 0; j4 < 32; ++j4) {
        float4 w = w4[wv][j4][l];
        float4 h4 = *reinterpret_cast<const float4*>(&hseg[4 * j4]);
        a0 = fmaf(w.x, h4.x, a0); a1 = fmaf(w.y, h4.y, a1);
        a2 = fmaf(w.z, h4.z, a2); a3 = fmaf(w.w, h4.w, a3);
      }
      float acc = (a0 + a1) + (a2 + a3);
      acc += __shfl_xor(acc, 1);
      acc += __shfl_xor(acc, 2);
      float full = acc + pre_v;
      int gbase = (l & 48) | (l & 3);
      float vi = __shfl(full, gbase), vf = __shfl(full, gbase | 4);
      float vg = __shfl(full, gbase | 8), vo = __shfl(full, gbase | 12);
      float si = 1.f / (1.f + __expf(-vi));
      float sf = 1.f / (1.f + __expf(-vf));
      float so = 1.f / (1.f + __expf(-vo));
      creg = sf * creg + si * tanhf(vg);
      float h = so * tanhf(creg);
      if ((l & 15) == 0) {
        int dim = d0w + (l >> 4);
        ull pvs = ((ull)(unsigned)(s + 1) << 32) | (unsigned)__float_as_uint(h);
        __hip_atomic_store(encX + (size_t)s * HID + dim, pvs, __ATOMIC_RELAXED,
                           __HIP_MEMORY_SCOPE_AGENT);
      }
    }
  } else {
    // ======================= dec role (8 dims/block) ========================
    const int blk = blockIdx.x - NBLK;          // 0..63
    const int o = l & 7;                         // k-octant (128 k each)
    const int c = l >> 3;                        // col-in-wave 0..7
    const int gq = c & 3;                        // gate
    const int dl = c >> 2;                       // dim-in-wave 0..1
    const int dim = blk * 8 + 2 * wv + dl;
    const int colw = gq * HID + dim;
    {
      const float* srcW = (o < 4)
          ? (decWh + (size_t)(o * 128) * G4 + colw)
          : (decWi + (size_t)(OBJ_IN + (o - 4) * 128) * G4 + colw);
#pragma unroll 4
      for (int j4 = 0; j4 < 32; ++j4) {
        float4 t;
        t.x = srcW[(size_t)(4 * j4 + 0) * G4];
        t.y = srcW[(size_t)(4 * j4 + 1) * G4];
        t.z = srcW[(size_t)(4 * j4 + 2) * G4];
        t.w = srcW[(size_t)(4 * j4 + 3) * G4];
        w4[wv][j4][l] = t;
      }
    }
    for (int i = tid; i < 1056; i += 256) hl[i] = 0.f;
    __syncthreads();

    float creg = 0.f;
    bool dead = false;
    for (int s = 0; s < T; ++s) {
      float pre_v = preD[(size_t)s * G4 + colw];
      if (wv == 0) {
        const ull* srcE = encX + (size_t)s * HID + l * 8;
        const ull* srcD = dechX + (size_t)(s - 1) * HID + l * 8;  // used iff s>0
        ull pe[8], pd[8];
        if (!dead) {
          int tries = 0;
          for (;;) {
            unsigned tminE = 0xFFFFFFFFu, tminD = 0xFFFFFFFFu;
#pragma unroll
            for (int j = 0; j < 8; ++j) {
              pe[j] = __hip_atomic_load(srcE + j, __ATOMIC_RELAXED, __HIP_MEMORY_SCOPE_AGENT);
              tminE = min(tminE, (unsigned)(pe[j] >> 32));
            }
            if (s > 0) {
#pragma unroll
              for (int j = 0; j < 8; ++j) {
                pd[j] = __hip_atomic_load(srcD + j, __ATOMIC_RELAXED, __HIP_MEMORY_SCOPE_AGENT);
                tminD = min(tminD, (unsigned)(pd[j] >> 32));
              }
            }
            bool ok = (tminE >= (unsigned)(s + 1)) && (s == 0 || tminD >= (unsigned)s);
            if (__all((int)ok)) break;
            if (++tries > SPIN_FUSED) { dead = true; break; }
            __builtin_amdgcn_s_sleep(2);
          }
        }
        if (dead) {
#pragma unroll
          for (int j = 0; j < 8; ++j) { pe[j] = 0ull; pd[j] = 0ull; }
        }
        const int ppD = 8 * l + 4 * (l >> 4);
        const int ppE = 528 + 8 * l + 4 * (l >> 4);
        if (s > 0) {
#pragma unroll
          for (int j = 0; j < 8; ++j) hl[ppD + j] = __uint_as_float((unsigned)pd[j]);
        }
#pragma unroll
        for (int j = 0; j < 8; ++j) hl[ppE + j] = __uint_as_float((unsigned)pe[j]);
      }
      __syncthreads();

      float a0 = 0.f, a1 = 0.f, a2 = 0.f, a3 = 0.f;
      const float* hseg = &hl[132 * o];
#pragma unroll
      for (int j4 = 0; j4 < 32; ++j4) {
        float4 w = w4[wv][j4][l];
        float4 h4 = *reinterpret_cast<const float4*>(&hseg[4 * j4]);
        a0 = fmaf(w.x, h4.x, a0); a1 = fmaf(w.y, h4.y, a1);
        a2 = fmaf(w.z, h4.z, a2); a3 = fmaf(w.w, h4.w, a3);
      }
      float acc = (a0 + a1) + (a2 + a3);
      acc += __shfl_xor(acc, 1);
      acc += __shfl_xor(acc, 2);
      acc += __shfl_xor(acc, 4);
      float full = acc + pre_v;
      int gb = (dl * 4) * 8;  // lanes {gb, gb+8, gb+16, gb+24} hold gates i,f,g,o
      float vi = __shfl(full, gb), vf = __shfl(full, gb + 8);
      float vg = __shfl(full, gb + 16), vo = __shfl(full, gb + 24);
      float si = 1.f / (1.f + __expf(-vi));
      float sf = 1.f / (1.f + __expf(-vf));
      float so = 1.f / (1.f + __expf(-vo));
      creg = sf * creg + si * tanhf(vg);
      float h = so * tanhf(creg);
      if ((l & 31) == 0) {  // lanes 0 (dl=0) and 32 (dl=1)
        ull pvs = ((ull)(unsigned)(s + 1) << 32) | (unsigned)__float_as_uint(h);
        __hip_atomic_store(dechX + (size_t)s * HID + dim, pvs, __ATOMIC_RELAXED,
                           __HIP_MEMORY_SCOPE_AGENT);
      }
    }
  }
}

// ----------------------------------------------------------------------------
// standalone edge scan — BYTE-IDENTICAL to the R11-proven kernel (parity ring)
// ----------------------------------------------------------------------------
__global__ __launch_bounds__(256, 1)
void lstm_scan_kernel(const float* __restrict__ pre, const float* __restrict__ Wh,
                      float* __restrict__ hs, ull* hg, int T) {
  __shared__ float4 w4[4][32][64];
  __shared__ float hl[532];
  const int tid = threadIdx.x;
  const int wv = tid >> 6;
  const int l = tid & 63;
  const int q = l >> 2, qt = l & 3, dq = q >> 2, gq = q & 3;
  const int d0w = blockIdx.x * 16 + wv * 4;
  const int colw = gq * HID + d0w + dq;
  {
    const float* base = Wh + (size_t)(qt * 128) * G4 + colw;
#pragma unroll 4
    for (int j4 = 0; j4 < 32; ++j4) {
      float4 t;
      t.x = base[(size_t)(4 * j4 + 0) * G4];
      t.y = base[(size_t)(4 * j4 + 1) * G4];
      t.z = base[(size_t)(4 * j4 + 2) * G4];
      t.w = base[(size_t)(4 * j4 + 3) * G4];
      w4[wv][j4][l] = t;
    }
  }
  for (int i = tid; i < 532; i += 256) hl[i] = 0.f;
  __syncthreads();
  float creg = 0.f;
  bool dead = false;
  for (int s = 0; s < T; ++s) {
    float pre_v = pre[(size_t)s * G4 + colw];
    if (s > 0) {
      if (wv == 0) {
        const ull* src = hg + ((s - 1) & 1) * HID + l * 8;
        ull pv[8];
        if (!dead) {
          int tries = 0;
          for (;;) {
            unsigned tmin = 0xFFFFFFFFu;
#pragma unroll
            for (int j = 0; j < 8; ++j) {
              pv[j] = __hip_atomic_load(src + j, __ATOMIC_RELAXED, __HIP_MEMORY_SCOPE_AGENT);
              tmin = min(tmin, (unsigned)(pv[j] >> 32));
            }
            if (__all((int)(tmin >= (unsigned)s))) break;
            if (++tries > SPIN_EDGE) { dead = true; break; }
            __builtin_amdgcn_s_sleep(2);
          }
        }
        if (dead) {
#pragma unroll
          for (int j = 0; j < 8; ++j) pv[j] = 0ull;
        }
        const int pp = 8 * l + 4 * (l >> 4);
#pragma unroll
        for (int j = 0; j < 8; ++j) hl[pp + j] = __uint_as_float((unsigned)pv[j]);
      }
      __syncthreads();
    }
    float a0 = 0.f, a1 = 0.f, a2 = 0.f, a3 = 0.f;
    const float* hseg = &hl[132 * qt];
#pragma unroll
    for (int j4 = 0; j4 < 32; ++j4) {
      float4 w = w4[wv][j4][l];
      float4 h4 = *reinterpret_cast<const float4*>(&hseg[4 * j4]);
      a0 = fmaf(w.x, h4.x, a0); a1 = fmaf(w.y, h4.y, a1);
      a2 = fmaf(w.z, h4.z, a2); a3 = fmaf(w.w, h4.w, a3);
    }
    float acc = (a0 + a1) + (a2 + a3);
    acc += __shfl_xor(acc, 1);
    acc += __shfl_xor(acc, 2);
    float full = acc + pre_v;
    int gbase = (l & 48) | (l & 3);
    float vi = __shfl(full, gbase), vf = __shfl(full, gbase | 4);
    float vg = __shfl(full, gbase | 8), vo = __shfl(full, gbase | 12);
    float si = 1.f / (1.f + __expf(-vi));
    float sf = 1.f / (1.f + __expf(-vf));
    float so = 1.f / (1.f + __expf(-vo));
    creg = sf * creg + si * tanhf(vg);
    float h = so * tanhf(creg);
    if ((l & 15) == 0) {
      int dim = d0w + (l >> 4);
      hs[(size_t)s * HID + dim] = h;
      ull pvs = ((ull)(unsigned)(s + 1) << 32) | (unsigned)__float_as_uint(h);
      __hip_atomic_store(hg + (s & 1) * HID + dim, pvs, __ATOMIC_RELAXED,
                         __HIP_MEMORY_SCOPE_AGENT);
    }
  }
}

// ----------------------------------------------------------------------------
__global__ void argmax_kernel(const float* __restrict__ dists, int* __restrict__ pred_i,
                              float* __restrict__ pred_f) {
  int r = blockIdx.x;
  int lane = threadIdx.x;
  float bv = -3.4e38f;
  int bi = NUM_CLASSES;
  for (int cc = lane; cc < NUM_CLASSES; cc += 64) {
    float v = dists[(size_t)r * NUM_CLASSES + cc];
    if (v > bv) { bv = v; bi = cc; }
  }
  for (int off = 32; off; off >>= 1) {
    float ov = __shfl_xor(bv, off);
    int oi = __shfl_xor(bi, off);
    if (ov > bv || (ov == bv && oi < bi)) { bv = ov; bi = oi; }
  }
  if (lane == 0) {
    pred_i[r] = bi;
    pred_f[r] = (float)bi;
  }
}

// ----------------------------------------------------------------------------
extern "C" void kernel_launch(void* const* d_in, const int* in_sizes, int n_in,
                              void* d_out, int out_size, void* d_ws, size_t ws_size,
                              hipStream_t stream) {
  const float* x        = (const float*)d_in[0];
  const float* odists   = (const float*)d_in[1];
  const float* box      = (const float*)d_in[2];
  const float* vobj     = (const float*)d_in[3];
  const float* vedge    = (const float*)d_in[4];
  const float* embed1   = (const float*)d_in[5];
  const float* embed2   = (const float*)d_in[6];
  const float* pos_W1   = (const float*)d_in[7];
  const float* pos_b1   = (const float*)d_in[8];
  const float* bn_gamma = (const float*)d_in[9];
  const float* bn_beta  = (const float*)d_in[10];
  const float* bn_mean  = (const float*)d_in[11];
  const float* bn_var   = (const float*)d_in[12];
  const float* pos_W2   = (const float*)d_in[13];
  const float* pos_b2   = (const float*)d_in[14];
  const float* obj_Wi   = (const float*)d_in[15];
  const float* obj_Wh   = (const float*)d_in[16];
  const float* obj_b    = (const float*)d_in[17];
  const float* dec_Wi   = (const float*)d_in[18];
  const float* dec_Wh   = (const float*)d_in[19];
  const float* dec_b    = (const float*)d_in[20];
  const float* out_W    = (const float*)d_in[21];
  const float* out_b    = (const float*)d_in[22];
  const float* edge_Wi  = (const float*)d_in[23];
  const float* edge_Wh  = (const float*)d_in[24];
  const float* edge_b   = (const float*)d_in[25];

  float* out = (float*)d_out;

  // workspace layout (70.4 MB; R12's executed overlap branch proved ws>=82.1MB)
  float* preO = (float*)d_ws;                           // 2064x2048
  float* preD = preO + (size_t)N_TOT * G4;              // 2064x2048
  float* bigA = preD + (size_t)N_TOT * G4;              // feats 2064x4424
  float* epre = bigA;                                   // 2064x2048 (feats dead)
  ull* encX   = (ull*)(bigA + (size_t)N_TOT * G4);      // 2064x512 tagged
  ull* dechX  = encX + (size_t)N_TOT * HID;             // 2064x512 tagged
  int* pred_i = (int*)(bigA + (size_t)N_TOT * OBJ_IN);  // 2048
  ull* hgE    = (ull*)(pred_i + N_OBJ);                 // 2x512 parity ring

  const size_t need_bytes =
      (2 * (size_t)N_TOT * G4 + (size_t)N_TOT * OBJ_IN) * 4 +
      (size_t)N_OBJ * 4 + 2 * HID * 8 + 256;
  if (ws_size < need_bytes) return;  // fail loudly, don't corrupt

  const size_t OUT_PRED = (size_t)N_OBJ * NUM_CLASSES;  // 309248
  const size_t OUT_EDGE = OUT_PRED + N_OBJ;             // 311296

  // 1) build feats in bigA
  copy_x_kernel<<<(N_OBJ * (OBJ_DIM / 4) + 255) / 256, 256, 0, stream>>>(x, bigA);
  {
    long n4 = (long)16 * OBJ_IN / 4;
    copy4_kernel<<<(unsigned)((n4 + 255) / 256), 256, 0, stream>>>(
        (const float4*)vobj, (float4*)(bigA + (size_t)N_OBJ * OBJ_IN), n4);
  }
  obj_embed_kernel<<<N_OBJ, 256, 0, stream>>>(odists, embed1, bigA);
  pos_kernel<<<N_OBJ, 128, 0, stream>>>(box, pos_W1, pos_b1, bn_gamma, bn_beta, bn_mean,
                                        bn_var, pos_W2, pos_b2, bigA);

  // 2) pre-activation GEMMs (read feats)
  gemm_kernel<0><<<dim3(32, 33), 256, 0, stream>>>(bigA, OBJ_IN, 1, obj_Wi, G4, obj_b,
                                                   preO, G4, N_TOT, G4, OBJ_IN);
  gemm_kernel<0><<<dim3(32, 33), 256, 0, stream>>>(bigA, OBJ_IN, 1, dec_Wi, G4, dec_b,
                                                   preD, G4, N_TOT, G4, OBJ_IN);

  // 3) zero the tagged exchanges (AFTER pre-GEMMs: encX/dechX alias feats tail)
  init_sync_kernel<<<1024, 256, 0, stream>>>((unsigned*)encX, 2 * N_TOT * HID * 2);
  init_sync_kernel<<<8, 256, 0, stream>>>((unsigned*)hgE, 2 * HID * 2);

  // 4) fused encoder+decoder pipeline (96 blocks, 1/CU)
  fused_scan_kernel<<<NBLK + NDEC, 256, 0, stream>>>(preO, obj_Wh, preD, dec_Wh, dec_Wi,
                                                     encX, dechX, N_TOT);

  // 5) edge pre (decomposed, validated R13), into epre (= bigA[0:16.9MB])
  gemm_kernel<0><<<dim3(32, 32), 256, 0, stream>>>(x, OBJ_DIM, 1, edge_Wi + (size_t)200 * G4,
                                                   G4, edge_b, epre, G4, N_OBJ, G4, OBJ_DIM);
  gemm_kernel<0><<<dim3(32, 1), 256, 0, stream>>>(vedge, EDGE_IN, 1, edge_Wi, G4, edge_b,
                                                  epre + (size_t)N_OBJ * G4, G4,
                                                  N_TOT - N_OBJ, G4, EDGE_IN);
  gemm_kernel<1><<<dim3(32, 32), 256, 0, stream>>>((const float*)encX, 2 * HID, 2,
                                                   edge_Wi + (size_t)4296 * G4, G4, nullptr,
                                                   epre, G4, N_OBJ, G4, HID);

  // 6) logits (strided from dechX) -> d_out, argmax, gathered embed2 part
  gemm_kernel<0><<<dim3(3, 32), 256, 0, stream>>>((const float*)dechX, 2 * HID, 2, out_W,
                                                  NUM_CLASSES, out_b, out, NUM_CLASSES,
                                                  N_OBJ, NUM_CLASSES, HID);
  argmax_kernel<<<N_OBJ, 64, 0, stream>>>(out, pred_i, out + OUT_PRED);
  gemm_gather_kernel<<<dim3(32, 32), 256, 0, stream>>>(embed2, pred_i, edge_Wi, epre,
                                                       N_OBJ, G4, EMBED);

  // 7) edge scan (R11-proven standalone); edgeh reuses preO (dead after fused)
  lstm_scan_kernel<<<NBLK, 256, 0, stream>>>(epre, edge_Wh, preO, hgE, N_TOT);
  copy4_kernel<<<1024, 256, 0, stream>>>((const float4*)preO, (float4*)(out + OUT_EDGE),
                                         (long)N_OBJ * HID / 4);
}

// Round 15
// 9856.516 us; speedup vs baseline: 2.4933x; 1.6929x over previous
//
#include <hip/hip_runtime.h>
#include <cstdint>
#include <cstddef>

#define N_OBJ 2048
#define NUM_CLASSES 151
#define EMBED 200
#define HID 512
#define OBJ_DIM 4096
#define POS 128
#define OBJ_IN 4424   // 4096+200+128
#define EDGE_IN 4808  // 200+4096+512
#define G4 2048       // 4*HID
#define TSTEPS 2048   // virtual rows are causally dead (outputs sliced [:2048])
#define SPIN_FUSED 12000
#define OUT_PRED 309248
#define OUT_EDGE 311296

typedef unsigned long long ull;

// ----------------------------------------------------------------------------
// utility kernels
// ----------------------------------------------------------------------------
__global__ void init_sync_kernel(unsigned* p, long n) {
  long i = blockIdx.x * (long)blockDim.x + threadIdx.x;
  long stride = (long)gridDim.x * blockDim.x;
  for (; i < n; i += stride) p[i] = 0u;
}

// objemb[r][0:200] = obj_dists_in[r] @ embed1  (compact, ld=200)
__global__ void obj_embed2_kernel(const float* __restrict__ dists,
                                  const float* __restrict__ embed1,
                                  float* __restrict__ objemb) {
  int r = blockIdx.x;
  __shared__ float drow[NUM_CLASSES];
  for (int c = threadIdx.x; c < NUM_CLASSES; c += blockDim.x)
    drow[c] = dists[(size_t)r * NUM_CLASSES + c];
  __syncthreads();
  for (int j = threadIdx.x; j < EMBED; j += blockDim.x) {
    float s = 0.f;
    for (int k = 0; k < NUM_CLASSES; ++k)
      s = fmaf(drow[k], embed1[(size_t)k * EMBED + j], s);
    objemb[(size_t)r * EMBED + j] = s;
  }
}

// posemb[r][0:128] = relu(BN(box@W1+b1)@W2+b2)  (compact, ld=128)
__global__ void pos2_kernel(const float* __restrict__ box,
                            const float* __restrict__ W1, const float* __restrict__ b1,
                            const float* __restrict__ gamma, const float* __restrict__ beta,
                            const float* __restrict__ mean, const float* __restrict__ var,
                            const float* __restrict__ W2, const float* __restrict__ b2,
                            float* __restrict__ posemb) {
  int r = blockIdx.x;
  __shared__ float h[32];
  __shared__ float bx[9];
  if (threadIdx.x < 9) bx[threadIdx.x] = box[(size_t)r * 9 + threadIdx.x];
  __syncthreads();
  if (threadIdx.x < 32) {
    float s = b1[threadIdx.x];
    for (int k = 0; k < 9; ++k) s = fmaf(bx[k], W1[k * 32 + threadIdx.x], s);
    s = (s - mean[threadIdx.x]) * (1.f / sqrtf(var[threadIdx.x] + 1e-5f)) * gamma[threadIdx.x]
        + beta[threadIdx.x];
    h[threadIdx.x] = s;
  }
  __syncthreads();
  int j = threadIdx.x;
  if (j < POS) {
    float s = b2[j];
    for (int k = 0; k < 32; ++k) s = fmaf(h[k], W2[k * POS + j], s);
    posemb[(size_t)r * POS + j] = fmaxf(s, 0.f);
  }
}

// ----------------------------------------------------------------------------
// 64x64 GEMM (R11-proven): C = A@B (+bias if !ACC, += if ACC), bounds-checked
// ----------------------------------------------------------------------------
template <int ACC>
__global__ __launch_bounds__(256)
void gemm_kernel(const float* __restrict__ A, int lda,
                 const float* __restrict__ B, int ldb,
                 const float* __restrict__ bias,
                 float* __restrict__ C, int ldc,
                 int M, int N, int K) {
  __shared__ __align__(16) float As[16][68];
  __shared__ __align__(16) float Bs[16][64];
  const int row0 = blockIdx.y * 64;
  const int col0 = blockIdx.x * 64;
  const int tid = threadIdx.x;
  const int tx = tid & 15, ty = tid >> 4;
  float acc[4][4] = {};

  for (int k0 = 0; k0 < K; k0 += 16) {
#pragma unroll
    for (int l = 0; l < 4; ++l) {
      int idx = tid + l * 256;
      int m = idx >> 4, kk = idx & 15;
      int gm = row0 + m, gk = k0 + kk;
      As[kk][m] = (gm < M && gk < K) ? A[(size_t)gm * lda + gk] : 0.f;
    }
#pragma unroll
    for (int l = 0; l < 4; ++l) {
      int idx = tid + l * 256;
      int kk = idx >> 6, n = idx & 63;
      int gk = k0 + kk, gn = col0 + n;
      Bs[kk][n] = (gk < K && gn < N) ? B[(size_t)gk * ldb + gn] : 0.f;
    }
    __syncthreads();
#pragma unroll
    for (int kk = 0; kk < 16; ++kk) {
      float4 a = *reinterpret_cast<const float4*>(&As[kk][ty * 4]);
      float4 b = *reinterpret_cast<const float4*>(&Bs[kk][tx * 4]);
      acc[0][0] = fmaf(a.x, b.x, acc[0][0]); acc[0][1] = fmaf(a.x, b.y, acc[0][1]);
      acc[0][2] = fmaf(a.x, b.z, acc[0][2]); acc[0][3] = fmaf(a.x, b.w, acc[0][3]);
      acc[1][0] = fmaf(a.y, b.x, acc[1][0]); acc[1][1] = fmaf(a.y, b.y, acc[1][1]);
      acc[1][2] = fmaf(a.y, b.z, acc[1][2]); acc[1][3] = fmaf(a.y, b.w, acc[1][3]);
      acc[2][0] = fmaf(a.z, b.x, acc[2][0]); acc[2][1] = fmaf(a.z, b.y, acc[2][1]);
      acc[2][2] = fmaf(a.z, b.z, acc[2][2]); acc[2][3] = fmaf(a.z, b.w, acc[2][3]);
      acc[3][0] = fmaf(a.w, b.x, acc[3][0]); acc[3][1] = fmaf(a.w, b.y, acc[3][1]);
      acc[3][2] = fmaf(a.w, b.z, acc[3][2]); acc[3][3] = fmaf(a.w, b.w, acc[3][3]);
    }
    __syncthreads();
  }
#pragma unroll
  for (int i = 0; i < 4; ++i) {
    int gm = row0 + ty * 4 + i;
    if (gm >= M) continue;
#pragma unroll
    for (int j = 0; j < 4; ++j) {
      int gn = col0 + tx * 4 + j;
      if (gn >= N) continue;
      size_t o = (size_t)gm * ldc + gn;
      if (ACC) C[o] += acc[i][j];
      else C[o] = acc[i][j] + (bias ? bias[gn] : 0.f);
    }
  }
}

// ----------------------------------------------------------------------------
// MEGA-FUSED pipeline: obj scan -> dec scan -> argmax -> edge scan, one
// dispatch, 176 blocks (obj[0,32) 16 dims; dec[32,96) 8 dims; argmax[96,112);
// edge[112,176) 8 dims). Exchange: full-array tagged pairs {tag=s+1, payload}
// (encX/dechX/edgeX per (step,dim) slot; predX per step), relaxed/agent
// atomics (only proven-safe codegen), zero-init per launch (poison-safe),
// no ring/lap hazards, no backpressure. Bounded spins + sticky dead-latch:
// worst case loud absmax fail, never a hang. Scan blocks: 135KB LDS -> 1/CU.
// ----------------------------------------------------------------------------
__device__ __forceinline__ void rec8_body(
    int blk, const float* __restrict__ pre, const float* __restrict__ Wh,
    const float* __restrict__ Wi2, ull* hXown, const ull* encXc,
    const ull* predX, const float* __restrict__ embT, float* outEdge,
    float4 (*w4)[32][64], float* hl, int* shPred) {
  const int tid = threadIdx.x;
  const int wv = tid >> 6;
  const int l = tid & 63;
  const int o = l & 7;          // k-octant (128 k each; o<4 = own-h, o>=4 = enc)
  const int c = l >> 3;         // col-in-wave 0..7
  const int gq = c & 3;         // gate
  const int dl = c >> 2;        // dim-in-wave 0..1
  const int dim = blk * 8 + 2 * wv + dl;
  const int colw = gq * HID + dim;
  {
    const float* srcW = (o < 4) ? (Wh + (size_t)(o * 128) * G4 + colw)
                                : (Wi2 + (size_t)((o - 4) * 128) * G4 + colw);
#pragma unroll 4
    for (int j4 = 0; j4 < 32; ++j4) {
      float4 t;
      t.x = srcW[(size_t)(4 * j4 + 0) * G4];
      t.y = srcW[(size_t)(4 * j4 + 1) * G4];
      t.z = srcW[(size_t)(4 * j4 + 2) * G4];
      t.w = srcW[(size_t)(4 * j4 + 3) * G4];
      w4[wv][j4][l] = t;
    }
  }
  for (int i = tid; i < 1056; i += 256) hl[i] = 0.f;
  __syncthreads();

  float creg = 0.f;
  bool dead = false;
  for (int s = 0; s < TSTEPS; ++s) {
    float pre_v = pre[(size_t)s * G4 + colw];
    if (wv == 0) {
      const ull* srcE = encXc + (size_t)s * HID + l * 8;
      const ull* srcH = hXown + (size_t)(s - 1) * HID + l * 8;  // deref iff s>0
      ull pe[8], ph[8], pp = 0;
      if (!dead) {
        int tries = 0;
        for (;;) {
          unsigned tE = 0xFFFFFFFFu, tH = 0xFFFFFFFFu, tP = 0xFFFFFFFFu;
#pragma unroll
          for (int j = 0; j < 8; ++j) {
            pe[j] = __hip_atomic_load(srcE + j, __ATOMIC_RELAXED, __HIP_MEMORY_SCOPE_AGENT);
            tE = min(tE, (unsigned)(pe[j] >> 32));
          }
          if (s > 0) {
#pragma unroll
            for (int j = 0; j < 8; ++j) {
              ph[j] = __hip_atomic_load(srcH + j, __ATOMIC_RELAXED, __HIP_MEMORY_SCOPE_AGENT);
              tH = min(tH, (unsigned)(ph[j] >> 32));
            }
          }
          if (predX) {
            pp = __hip_atomic_load(predX + s, __ATOMIC_RELAXED, __HIP_MEMORY_SCOPE_AGENT);
            tP = (unsigned)(pp >> 32);
          }
          bool ok = (tE >= (unsigned)(s + 1)) && (s == 0 || tH >= (unsigned)s) &&
                    (!predX || tP >= (unsigned)(s + 1));
          if (__all((int)ok)) break;
          if (++tries > SPIN_FUSED) { dead = true; break; }
          __builtin_amdgcn_s_sleep(2);
        }
      }
      if (dead) {
#pragma unroll
        for (int j = 0; j < 8; ++j) { pe[j] = 0ull; ph[j] = 0ull; }
        pp = 0;
      }
      const int ppH = 8 * l + 4 * (l >> 4);
      const int ppE = 528 + ppH;
      if (s > 0) {
#pragma unroll
        for (int j = 0; j < 8; ++j) hl[ppH + j] = __uint_as_float((unsigned)ph[j]);
      }
#pragma unroll
      for (int j = 0; j < 8; ++j) hl[ppE + j] = __uint_as_float((unsigned)pe[j]);
      if (predX && l == 0) *shPred = (int)(unsigned)(pp & 0xFFFFFFFFull);
    }
    __syncthreads();

    float emb = 0.f;
    if (embT) emb = embT[(size_t)(*shPred) * G4 + colw];

    float a0 = 0.f, a1 = 0.f, a2 = 0.f, a3 = 0.f;
    const float* hseg = &hl[132 * o];
#pragma unroll
    for (int j4 = 0; j4 < 32; ++j4) {
      float4 w = w4[wv][j4][l];
      float4 h4 = *reinterpret_cast<const float4*>(&hseg[4 * j4]);
      a0 = fmaf(w.x, h4.x, a0); a1 = fmaf(w.y, h4.y, a1);
      a2 = fmaf(w.z, h4.z, a2); a3 = fmaf(w.w, h4.w, a3);
    }
    float acc = (a0 + a1) + (a2 + a3);
    acc += __shfl_xor(acc, 1);
    acc += __shfl_xor(acc, 2);
    acc += __shfl_xor(acc, 4);
    float full = acc + pre_v + emb;
    int gb = dl * 32;  // lanes gb, gb+8, gb+16, gb+24 hold gates i,f,g,o (R14-verified)
    float vi = __shfl(full, gb), vf = __shfl(full, gb + 8);
    float vg = __shfl(full, gb + 16), vo = __shfl(full, gb + 24);
    float si = 1.f / (1.f + __expf(-vi));
    float sf = 1.f / (1.f + __expf(-vf));
    float so = 1.f / (1.f + __expf(-vo));
    creg = sf * creg + si * tanhf(vg);
    float h = so * tanhf(creg);
    if ((l & 31) == 0) {
      if (outEdge) outEdge[(size_t)s * HID + dim] = h;
      ull pvs = ((ull)(unsigned)(s + 1) << 32) | (unsigned)__float_as_uint(h);
      __hip_atomic_store(hXown + (size_t)s * HID + dim, pvs, __ATOMIC_RELAXED,
                         __HIP_MEMORY_SCOPE_AGENT);
    }
  }
}

__global__ __launch_bounds__(256, 1)
void fused_all_kernel(const float* __restrict__ preO, const float* __restrict__ objWh,
                      const float* __restrict__ preD, const float* __restrict__ decWh,
                      const float* __restrict__ decWi2,
                      const float* __restrict__ epre, const float* __restrict__ embT,
                      const float* __restrict__ edgeWh, const float* __restrict__ edgeWi2,
                      const float* __restrict__ outW, const float* __restrict__ outB,
                      ull* encX, ull* dechX, ull* edgeX, ull* predX,
                      float* out) {
  __shared__ float4 w4[4][32][64];   // 128 KB
  __shared__ float hl[1056];         // scan h staging / argmax dh+logits
  __shared__ int shPred;
  const int bid = blockIdx.x;
  const int tid = threadIdx.x;
  const int wv = tid >> 6;
  const int l = tid & 63;

  if (bid < 32) {
    // ========================= obj role (16 dims) ==========================
    const int q = l >> 2, qt = l & 3, dq = q >> 2, gq = q & 3;
    const int d0w = bid * 16 + wv * 4;
    const int colw = gq * HID + d0w + dq;
    {
      const float* base = objWh + (size_t)(qt * 128) * G4 + colw;
#pragma unroll 4
      for (int j4 = 0; j4 < 32; ++j4) {
        float4 t;
        t.x = base[(size_t)(4 * j4 + 0) * G4];
        t.y = base[(size_t)(4 * j4 + 1) * G4];
        t.z = base[(size_t)(4 * j4 + 2) * G4];
        t.w = base[(size_t)(4 * j4 + 3) * G4];
        w4[wv][j4][l] = t;
      }
    }
    for (int i = tid; i < 532; i += 256) hl[i] = 0.f;
    __syncthreads();

    float creg = 0.f;
    bool dead = false;
    for (int s = 0; s < TSTEPS; ++s) {
      float pre_v = preO[(size_t)s * G4 + colw];
      if (s > 0) {
        if (wv == 0) {
          const ull* src = encX + (size_t)(s - 1) * HID + l * 8;
          ull pv[8];
          if (!dead) {
            int tries = 0;
            for (;;) {
              unsigned tmin = 0xFFFFFFFFu;
#pragma unroll
              for (int j = 0; j < 8; ++j) {
                pv[j] = __hip_atomic_load(src + j, __ATOMIC_RELAXED, __HIP_MEMORY_SCOPE_AGENT);
                tmin = min(tmin, (unsigned)(pv[j] >> 32));
              }
              if (__all((int)(tmin >= (unsigned)s))) break;
              if (++tries > SPIN_FUSED) { dead = true; break; }
              __builtin_amdgcn_s_sleep(2);
            }
          }
          if (dead) {
#pragma unroll
            for (int j = 0; j < 8; ++j) pv[j] = 0ull;
          }
          const int pp = 8 * l + 4 * (l >> 4);
#pragma unroll
          for (int j = 0; j < 8; ++j) hl[pp + j] = __uint_as_float((unsigned)pv[j]);
        }
        __syncthreads();
      }
      float a0 = 0.f, a1 = 0.f, a2 = 0.f, a3 = 0.f;
      const float* hseg = &hl[132 * qt];
#pragma unroll
      for (int j4 = 0; j4 < 32; ++j4) {
        float4 w = w4[wv][j4][l];
        float4 h4 = *reinterpret_cast<const float4*>(&hseg[4 * j4]);
        a0 = fmaf(w.x, h4.x, a0); a1 = fmaf(w.y, h4.y, a1);
        a2 = fmaf(w.z, h4.z, a2); a3 = fmaf(w.w, h4.w, a3);
      }
      float acc = (a0 + a1) + (a2 + a3);
      acc += __shfl_xor(acc, 1);
      acc += __shfl_xor(acc, 2);
      float full = acc + pre_v;
      int gbase = (l & 48) | (l & 3);
      float vi = __shfl(full, gbase), vf = __shfl(full, gbase | 4);
      float vg = __shfl(full, gbase | 8), vo = __shfl(full, gbase | 12);
      float si = 1.f / (1.f + __expf(-vi));
      float sf = 1.f / (1.f + __expf(-vf));
      float so = 1.f / (1.f + __expf(-vo));
      creg = sf * creg + si * tanhf(vg);
      float h = so * tanhf(creg);
      if ((l & 15) == 0) {
        int dim = d0w + (l >> 4);
        ull pvs = ((ull)(unsigned)(s + 1) << 32) | (unsigned)__float_as_uint(h);
        __hip_atomic_store(encX + (size_t)s * HID + dim, pvs, __ATOMIC_RELAXED,
                           __HIP_MEMORY_SCOPE_AGENT);
      }
    }
  } else if (bid < 96) {
    // ========================= dec role (8 dims) ===========================
    rec8_body(bid - 32, preD, decWh, decWi2, dechX, encX,
              nullptr, nullptr, nullptr, w4, hl, &shPred);
  } else if (bid < 112) {
    // ===================== argmax role (rows a, a+16, ...) =================
    const int a = bid - 96;
    float* dh = hl;            // [0,512)
    float* lg = hl + 512;      // [512,663)
    bool dead = false;
    for (int r = a; r < TSTEPS; r += 16) {
      if (wv == 0) {
        const ull* src = dechX + (size_t)r * HID + l * 8;
        ull pv[8];
        if (!dead) {
          int tries = 0;
          for (;;) {
            unsigned tmin = 0xFFFFFFFFu;
#pragma unroll
            for (int j = 0; j < 8; ++j) {
              pv[j] = __hip_atomic_load(src + j, __ATOMIC_RELAXED, __HIP_MEMORY_SCOPE_AGENT);
              tmin = min(tmin, (unsigned)(pv[j] >> 32));
            }
            if (__all((int)(tmin >= (unsigned)(r + 1)))) break;
            if (++tries > SPIN_FUSED) { dead = true; break; }
            __builtin_amdgcn_s_sleep(2);
          }
        }
        if (dead) {
#pragma unroll
          for (int j = 0; j < 8; ++j) pv[j] = 0ull;
        }
#pragma unroll
        for (int j = 0; j < 8; ++j) dh[l * 8 + j] = __uint_as_float((unsigned)pv[j]);
      }
      __syncthreads();
      if (tid < NUM_CLASSES) {
        float s2 = outB[tid];
#pragma unroll 8
        for (int k = 0; k < HID; ++k)
          s2 = fmaf(dh[k], outW[(size_t)k * NUM_CLASSES + tid], s2);
        lg[tid] = s2;
        out[(size_t)r * NUM_CLASSES + tid] = s2;
      }
      __syncthreads();
      if (wv == 0) {
        float bv = -3.4e38f;
        int bi = NUM_CLASSES;
        for (int cc = l; cc < NUM_CLASSES; cc += 64) {
          float v = lg[cc];
          if (v > bv) { bv = v; bi = cc; }
        }
        for (int off = 32; off; off >>= 1) {
          float ov = __shfl_xor(bv, off);
          int oi = __shfl_xor(bi, off);
          if (ov > bv || (ov == bv && oi < bi)) { bv = ov; bi = oi; }
        }
        if (l == 0) {
          out[OUT_PRED + r] = (float)bi;
          ull pvs = ((ull)(unsigned)(r + 1) << 32) | (unsigned)bi;
          __hip_atomic_store(predX + r, pvs, __ATOMIC_RELAXED, __HIP_MEMORY_SCOPE_AGENT);
        }
      }
      __syncthreads();
    }
  } else {
    // ========================= edge role (8 dims) ==========================
    rec8_body(bid - 112, epre, edgeWh, edgeWi2, edgeX, encX,
              predX, embT, out + OUT_EDGE, w4, hl, &shPred);
  }
}

// ----------------------------------------------------------------------------
extern "C" void kernel_launch(void* const* d_in, const int* in_sizes, int n_in,
                              void* d_out, int out_size, void* d_ws, size_t ws_size,
                              hipStream_t stream) {
  const float* x        = (const float*)d_in[0];
  const float* odists   = (const float*)d_in[1];
  const float* box      = (const float*)d_in[2];
  const float* embed1   = (const float*)d_in[5];
  const float* embed2   = (const float*)d_in[6];
  const float* pos_W1   = (const float*)d_in[7];
  const float* pos_b1   = (const float*)d_in[8];
  const float* bn_gamma = (const float*)d_in[9];
  const float* bn_beta  = (const float*)d_in[10];
  const float* bn_mean  = (const float*)d_in[11];
  const float* bn_var   = (const float*)d_in[12];
  const float* pos_W2   = (const float*)d_in[13];
  const float* pos_b2   = (const float*)d_in[14];
  const float* obj_Wi   = (const float*)d_in[15];
  const float* obj_Wh   = (const float*)d_in[16];
  const float* obj_b    = (const float*)d_in[17];
  const float* dec_Wi   = (const float*)d_in[18];
  const float* dec_Wh   = (const float*)d_in[19];
  const float* dec_b    = (const float*)d_in[20];
  const float* out_W    = (const float*)d_in[21];
  const float* out_b    = (const float*)d_in[22];
  const float* edge_Wi  = (const float*)d_in[23];
  const float* edge_Wh  = (const float*)d_in[24];
  const float* edge_b   = (const float*)d_in[25];

  float* out = (float*)d_out;

  // workspace layout (79.4 MB; R12's executed overlap branch proved ws>=82.5MB)
  float* preO   = (float*)d_ws;                        // 2048x2048
  float* preD   = preO + (size_t)TSTEPS * G4;          // 2048x2048
  float* epre   = preD + (size_t)TSTEPS * G4;          // 2048x2048
  float* objemb = epre + (size_t)TSTEPS * G4;          // 2048x200
  float* posemb = objemb + (size_t)TSTEPS * EMBED;     // 2048x128
  float* embT   = posemb + (size_t)TSTEPS * POS;       // 151x2048
  ull* encX  = (ull*)(embT + (size_t)NUM_CLASSES * G4);// 2048x512 tagged
  ull* dechX = encX + (size_t)TSTEPS * HID;            // 2048x512 tagged
  ull* edgeX = dechX + (size_t)TSTEPS * HID;           // 2048x512 tagged
  ull* predX = edgeX + (size_t)TSTEPS * HID;           // 2048 tagged

  const size_t need_bytes =
      ((size_t)3 * TSTEPS * G4 + (size_t)TSTEPS * (EMBED + POS) +
       (size_t)NUM_CLASSES * G4) * 4 +
      ((size_t)3 * TSTEPS * HID + TSTEPS) * 8 + 256;
  if (ws_size < need_bytes) return;  // fail loudly, don't corrupt

  // 1) small embeds (compact)
  obj_embed2_kernel<<<TSTEPS, 256, 0, stream>>>(odists, embed1, objemb);
  pos2_kernel<<<TSTEPS, 128, 0, stream>>>(box, pos_W1, pos_b1, bn_gamma, bn_beta, bn_mean,
                                          bn_var, pos_W2, pos_b2, posemb);

  // 2) zero all tagged exchanges (poison-safe; required every launch)
  init_sync_kernel<<<2048, 256, 0, stream>>>((unsigned*)encX,
                                             ((long)3 * TSTEPS * HID + TSTEPS) * 2);

  // 3) pre-activation GEMMs, K-decomposed (no feats materialization)
  gemm_kernel<0><<<dim3(32, 32), 256, 0, stream>>>(x, OBJ_DIM, obj_Wi, G4, obj_b,
                                                   preO, G4, TSTEPS, G4, OBJ_DIM);
  gemm_kernel<1><<<dim3(32, 32), 256, 0, stream>>>(objemb, EMBED, obj_Wi + (size_t)4096 * G4,
                                                   G4, nullptr, preO, G4, TSTEPS, G4, EMBED);
  gemm_kernel<1><<<dim3(32, 32), 256, 0, stream>>>(posemb, POS, obj_Wi + (size_t)4296 * G4,
                                                   G4, nullptr, preO, G4, TSTEPS, G4, POS);
  gemm_kernel<0><<<dim3(32, 32), 256, 0, stream>>>(x, OBJ_DIM, dec_Wi, G4, dec_b,
                                                   preD, G4, TSTEPS, G4, OBJ_DIM);
  gemm_kernel<1><<<dim3(32, 32), 256, 0, stream>>>(objemb, EMBED, dec_Wi + (size_t)4096 * G4,
                                                   G4, nullptr, preD, G4, TSTEPS, G4, EMBED);
  gemm_kernel<1><<<dim3(32, 32), 256, 0, stream>>>(posemb, POS, dec_Wi + (size_t)4296 * G4,
                                                   G4, nullptr, preD, G4, TSTEPS, G4, POS);
  gemm_kernel<0><<<dim3(32, 32), 256, 0, stream>>>(x, OBJ_DIM, edge_Wi + (size_t)200 * G4,
                                                   G4, edge_b, epre, G4, TSTEPS, G4, OBJ_DIM);
  gemm_kernel<0><<<dim3(32, 3), 256, 0, stream>>>(embed2, EMBED, edge_Wi, G4, nullptr,
                                                  embT, G4, NUM_CLASSES, G4, EMBED);

  // 4) the mega-fused pipeline: all three scans + logits + argmax + outputs
  fused_all_kernel<<<176, 256, 0, stream>>>(preO, obj_Wh, preD, dec_Wh,
                                            dec_Wi + (size_t)OBJ_IN * G4,
                                            epre, embT, edge_Wh,
                                            edge_Wi + (size_t)4296 * G4,
                                            out_W, out_b,
                                            encX, dechX, edgeX, predX, out);
}